// Round 7
// baseline (184.360 us; speedup 1.0000x reference)
//
#include <hip/hip_runtime.h>
#include <hip/hip_bf16.h>
#include <math.h>

// ---------------------------------------------------------------------------
// MoNet regression on icosphere graphs.
//   * edge_dst = repeat(arange(n), 6)  -> node i owns edges [6i, 6i+6)
//   * hex_pool keeps only first L rows; relu commutes with max-pool
//   * gmm_conv folded to node-level GEMM:
//       A[i, k*cin+c] = (1/6) sum_e w[e,k] * x[src[e], c]
//       out = relu( [A|x] @ [G'|root] + b ),  G'[k*cin+c, o] = g[c, k*cout+o]
// v5: fused L6 (build_A+GEMM in one kernel, K=16), z-split GEMMs write raw
// partials, fused reduce+bias+relu+hexpool, fused L3 reduce+pool+head1.
// GEMM: 64x64 tile, 4x4 acc, KG<=2 in-block k-groups (1024 threads spills
// under the 64-VGPR cap — R4 lesson) + grid.z split-K.  13 dispatches total.
// ---------------------------------------------------------------------------

#define GEPS 1e-15f

// ---------------- build_A (L5/L4/L3) ---------------------------------------
template <int CIN>
__global__ __launch_bounds__(256) void build_A_kern(
    const float* __restrict__ x,      // (n_src, CIN)
    const int*   __restrict__ src,    // (6n)
    const float* __restrict__ pseudo, // (6n, 3)
    const float* __restrict__ mu,     // (3,3)
    const float* __restrict__ sigma,  // (3,3)
    float* __restrict__ A,            // (n, 3*CIN)
    int n)
{
    constexpr int NB = 256 / CIN;
    constexpr int NE = NB * 6;
    __shared__ float s_w[NE * 3];
    __shared__ int   s_src[NE];
    __shared__ float s_mu[9], s_sig[9];

    const int tid = threadIdx.x;
    if (tid < 9) { s_mu[tid] = mu[tid]; s_sig[tid] = sigma[tid]; }
    __syncthreads();

    const int ebase = blockIdx.x * NE;
    const int nE = n * 6;
    for (int t = tid; t < NE; t += 256) {
        int e = ebase + t;
        if (e < nE) s_src[t] = src[e];
    }
    for (int t = tid; t < NE * 3; t += 256) {
        int e_l = t / 3, k = t - e_l * 3;
        int e = ebase + e_l;
        if (e < nE) {
            float s = 0.f;
#pragma unroll
            for (int d = 0; d < 3; ++d) {
                float diff = pseudo[e * 3 + d] - s_mu[k * 3 + d];
                float sg = s_sig[k * 3 + d];
                s += diff * diff / (sg * sg + GEPS);
            }
            s_w[t] = expf(-0.5f * s);
        }
    }
    __syncthreads();

    const int il = tid / CIN;
    const int c  = tid - il * CIN;
    const int i  = blockIdx.x * NB + il;
    if (i < n) {
        float a0 = 0.f, a1 = 0.f, a2 = 0.f;
#pragma unroll
        for (int e = 0; e < 6; ++e) {
            int s = s_src[il * 6 + e];
            float xv = x[s * CIN + c];
            const float* wp = &s_w[(il * 6 + e) * 3];
            a0 += wp[0] * xv; a1 += wp[1] * xv; a2 += wp[2] * xv;
        }
        const float inv6 = 1.f / 6.f;
        float* Ai = &A[i * (3 * CIN)];
        Ai[0 * CIN + c] = a0 * inv6;
        Ai[1 * CIN + c] = a1 * inv6;
        Ai[2 * CIN + c] = a2 * inv6;
    }
}

// ---------------- fused L6 conv (cin=4, K=16, cout=64) ----------------------
__global__ __launch_bounds__(256) void conv6_fused(
    const float* __restrict__ x,      // (n,4)
    const int*   __restrict__ src,    // (6n)
    const float* __restrict__ pseudo, // (6n,3)
    const float* __restrict__ mu,     // (3,3)
    const float* __restrict__ sigma,  // (3,3)
    const float* __restrict__ g,      // (4,192)
    const float* __restrict__ root,   // (4,64)
    const float* __restrict__ bias,   // (64)
    float* __restrict__ outc,         // (n,64)
    int n)
{
    __shared__ float Bs[16][68];      // [A-rows|x-rows] weight tile
    __shared__ float xle[64][6][4];   // gathered neighbor features
    __shared__ float wle[64][19];     // 6 edges x 3 kernels (+pad)
    __shared__ float Als[64][17];     // per-node [A(12)|x(4)] (+pad)

    const int t = threadIdx.x;
    const int node0 = blockIdx.x * 64;
    const int nE = n * 6;

    float muv[9], sgv[9];
#pragma unroll
    for (int q = 0; q < 9; ++q) { muv[q] = mu[q]; sgv[q] = sigma[q]; }

    // stage B: rows 0..11 = G'[k*4+c][o], rows 12..15 = root
    for (int idx = t; idx < 1024; idx += 256) {
        int jj = idx >> 6, o = idx & 63;
        float v;
        if (jj < 12) { int k = jj >> 2, c = jj & 3; v = g[c * 192 + k * 64 + o]; }
        else v = root[(jj - 12) * 64 + o];
        Bs[jj][o] = v;
    }
    // gather x + compute gaussian weights per edge
    for (int e = t; e < 384; e += 256) {
        int ge = node0 * 6 + e;
        int il = e / 6, el = e - il * 6;
        float4 xv = make_float4(0.f, 0.f, 0.f, 0.f);
        float w0 = 0.f, w1 = 0.f, w2 = 0.f;
        if (ge < nE) {
            xv = *(const float4*)&x[src[ge] * 4];
            float p0 = pseudo[ge * 3 + 0], p1 = pseudo[ge * 3 + 1], p2 = pseudo[ge * 3 + 2];
#pragma unroll
            for (int k = 0; k < 3; ++k) {
                float d0 = p0 - muv[k * 3 + 0], d1 = p1 - muv[k * 3 + 1], d2 = p2 - muv[k * 3 + 2];
                float s0 = sgv[k * 3 + 0], s1 = sgv[k * 3 + 1], s2 = sgv[k * 3 + 2];
                float s = d0 * d0 / (s0 * s0 + GEPS) + d1 * d1 / (s1 * s1 + GEPS)
                        + d2 * d2 / (s2 * s2 + GEPS);
                float w = expf(-0.5f * s);
                if (k == 0) w0 = w; else if (k == 1) w1 = w; else w2 = w;
            }
        }
        *(float4*)&xle[il][el][0] = xv;
        wle[il][el * 3 + 0] = w0; wle[il][el * 3 + 1] = w1; wle[il][el * 3 + 2] = w2;
    }
    // own features -> Als[:, 12..15]
    if (t < 64) {
        float4 xv = (node0 + t < n) ? *(const float4*)&x[(size_t)(node0 + t) * 4]
                                    : make_float4(0.f, 0.f, 0.f, 0.f);
        Als[t][12] = xv.x; Als[t][13] = xv.y; Als[t][14] = xv.z; Als[t][15] = xv.w;
    }
    __syncthreads();
    // A entries: 64 nodes x 12
    for (int ent = t; ent < 768; ent += 256) {
        int il = ent / 12, j = ent - il * 12;
        int k = j >> 2, c = j & 3;
        float a = 0.f;
#pragma unroll
        for (int e = 0; e < 6; ++e)
            a += wle[il][e * 3 + k] * xle[il][e][c];
        Als[il][j] = a * (1.f / 6.f);
    }
    __syncthreads();
    // out[node, 0..63] = relu(a16 . B + bias)
    {
        int il = t >> 2, og = (t & 3) * 16;
        if (node0 + il < n) {
            float acc[16];
#pragma unroll
            for (int q = 0; q < 16; ++q) acc[q] = 0.f;
#pragma unroll
            for (int j = 0; j < 16; ++j) {
                float a = Als[il][j];
#pragma unroll
                for (int q = 0; q < 16; ++q)
                    acc[q] += a * Bs[j][og + q];
            }
            float* po = &outc[(size_t)(node0 + il) * 64 + og];
#pragma unroll
            for (int q = 0; q < 16; q += 4) {
                float4 v;
                v.x = fmaxf(acc[q + 0] + bias[og + q + 0], 0.f);
                v.y = fmaxf(acc[q + 1] + bias[og + q + 1], 0.f);
                v.z = fmaxf(acc[q + 2] + bias[og + q + 2], 0.f);
                v.w = fmaxf(acc[q + 3] + bias[og + q + 3], 0.f);
                *(float4*)&po[q] = v;
            }
        }
    }
}

// ---------------- GEMM: 64x64 tile, 4x4 acc, KG in-block + grid.z split-K ---
#define LOAD3(kt)                                                             \
    {                                                                         \
        int jA = k0 + (kt) * 16 + lj;                                         \
        if (gi_l < n) {                                                       \
            ra = (jA < K3) ? *(const float4*)&A[gi_l * K3 + jA]               \
                           : *(const float4*)&x[gi_l * cin + (jA - K3)];      \
        } else { ra = make_float4(0.f, 0.f, 0.f, 0.f); }                      \
        int jB = k0 + (kt) * 16 + lkr;                                        \
        if (jB < K3) {                                                        \
            int kq = jB / cin, c = jB - kq * cin;                             \
            rb = *(const float4*)&g[c * (3 * cout) + kq * cout + bn + lc];    \
        } else {                                                              \
            rb = *(const float4*)&root[(jB - K3) * cout + bn + lc];           \
        }                                                                     \
    }

#define STORE3(b_)                                                            \
    {                                                                         \
        As[grp][b_][lj + 0][lr] = ra.x;                                       \
        As[grp][b_][lj + 1][lr] = ra.y;                                       \
        As[grp][b_][lj + 2][lr] = ra.z;                                       \
        As[grp][b_][lj + 3][lr] = ra.w;                                       \
        *(float4*)&Bs[grp][b_][lkr][lc] = rb;                                 \
    }

template <int KG, bool SPLIT>
__global__ __launch_bounds__(256 * KG) void gemm_node4(
    const float* __restrict__ A,    // (n, 3*cin)
    const float* __restrict__ x,    // (n, cin)
    const float* __restrict__ g,    // (cin, 3*cout)
    const float* __restrict__ root, // (cin, cout)
    const float* __restrict__ bias, // (cout)   (unused when SPLIT)
    float* __restrict__ out,        // (n, cout) or partials (nz, n, cout)
    int n, int cin, int cout)
{
    __shared__ float As[KG][2][16][68];
    __shared__ float Bs[KG][2][16][64];

    const int tid = threadIdx.x;
    const int grp = tid >> 8;
    const int t   = tid & 255;

    const int bm = blockIdx.x * 64;
    const int bn = blockIdx.y * 64;
    const int K3 = 3 * cin;
    const int KK = 4 * cin;
    const int nz = SPLIT ? gridDim.z : 1;
    const int chunk = KK / (nz * KG);
    const int k0 = (blockIdx.z * KG + grp) * chunk;
    const int nkt = chunk >> 4;

    const int lr  = t & 63;
    const int lj  = (t >> 6) * 4;
    const int gi_l = bm + lr;
    const int lkr = t >> 4;
    const int lc  = (t & 15) * 4;

    const int row0 = (t >> 4) * 4;
    const int col0 = (t & 15) * 4;

    float acc[4][4] = {};
    float4 ra, rb;

    LOAD3(0);
    STORE3(0);
    __syncthreads();

    int buf = 0;
    for (int kt = 0; kt < nkt; ++kt) {
        if (kt + 1 < nkt) LOAD3(kt + 1);
#pragma unroll
        for (int kk = 0; kk < 16; ++kk) {
            float4 a = *(const float4*)&As[grp][buf][kk][row0];
            float4 b = *(const float4*)&Bs[grp][buf][kk][col0];
            acc[0][0] += a.x * b.x; acc[0][1] += a.x * b.y;
            acc[0][2] += a.x * b.z; acc[0][3] += a.x * b.w;
            acc[1][0] += a.y * b.x; acc[1][1] += a.y * b.y;
            acc[1][2] += a.y * b.z; acc[1][3] += a.y * b.w;
            acc[2][0] += a.z * b.x; acc[2][1] += a.z * b.y;
            acc[2][2] += a.z * b.z; acc[2][3] += a.z * b.w;
            acc[3][0] += a.w * b.x; acc[3][1] += a.w * b.y;
            acc[3][2] += a.w * b.z; acc[3][3] += a.w * b.w;
        }
        if (kt + 1 < nkt) {
            STORE3(buf ^ 1);
            __syncthreads();
            buf ^= 1;
        }
    }

    __syncthreads();
    float* Rs0 = (float*)As;

#define WRITE_R(R)                                                            \
    {                                                                         \
        _Pragma("unroll")                                                     \
        for (int i2 = 0; i2 < 4; ++i2)                                        \
            *(float4*)&(R)[(row0 + i2) * 64 + col0] =                         \
                make_float4(acc[i2][0], acc[i2][1], acc[i2][2], acc[i2][3]);  \
    }
#define ADD_R(R)                                                              \
    {                                                                         \
        _Pragma("unroll")                                                     \
        for (int i2 = 0; i2 < 4; ++i2) {                                      \
            float4 r = *(const float4*)&(R)[(row0 + i2) * 64 + col0];         \
            acc[i2][0] += r.x; acc[i2][1] += r.y;                             \
            acc[i2][2] += r.z; acc[i2][3] += r.w;                             \
        }                                                                     \
    }

    if constexpr (KG == 2) {
        if (grp == 1) WRITE_R(Rs0);
        __syncthreads();
        if (grp == 0) ADD_R(Rs0);
    }

    if (grp == 0) {
        if constexpr (SPLIT) {
            float* po = &out[(size_t)blockIdx.z * n * cout];
#pragma unroll
            for (int i2 = 0; i2 < 4; ++i2) {
                int gi = bm + row0 + i2;
                if (gi < n)
                    *(float4*)&po[gi * cout + bn + col0] =
                        make_float4(acc[i2][0], acc[i2][1], acc[i2][2], acc[i2][3]);
            }
        } else {
            float4 bv = *(const float4*)&bias[bn + col0];
#pragma unroll
            for (int i2 = 0; i2 < 4; ++i2) {
                int gi = bm + row0 + i2;
                if (gi < n) {
                    float4 v;
                    v.x = fmaxf(acc[i2][0] + bv.x, 0.f);
                    v.y = fmaxf(acc[i2][1] + bv.y, 0.f);
                    v.z = fmaxf(acc[i2][2] + bv.z, 0.f);
                    v.w = fmaxf(acc[i2][3] + bv.w, 0.f);
                    *(float4*)&out[gi * cout + bn + col0] = v;
                }
            }
        }
    }
}

// ---------------- plain hexpool (L6) ----------------------------------------
__global__ void hexpool_kern(const float* __restrict__ xin,
                             const int* __restrict__ hx,
                             float* __restrict__ out, int L, int C)
{
    int idx = blockIdx.x * blockDim.x + threadIdx.x;
    int C4 = C >> 2;
    int total = L * C4;
    if (idx >= total) return;
    int i = idx / C4, c4 = (idx - i * C4) * 4;
    const int* h = &hx[i * 7];
    float4 m = make_float4(-INFINITY, -INFINITY, -INFINITY, -INFINITY);
#pragma unroll
    for (int j = 0; j < 7; ++j) {
        float4 v = *(const float4*)&xin[h[j] * C + c4];
        m.x = fmaxf(m.x, v.x); m.y = fmaxf(m.y, v.y);
        m.z = fmaxf(m.z, v.z); m.w = fmaxf(m.w, v.w);
    }
    *(float4*)&out[i * C + c4] = m;
}

// ---------------- fused z-reduce + bias + relu + hexpool (L5/L4) ------------
__global__ void hexpool_reduce_kern(
    const float* __restrict__ part,  // (nz, n, C)
    const int*   __restrict__ hx,    // (n,7) — first L rows used
    const float* __restrict__ bias,  // (C)
    float* __restrict__ out,         // (L, C)
    int L, int C, int n, int nz)
{
    int idx = blockIdx.x * blockDim.x + threadIdx.x;
    int C4 = C >> 2;
    int total = L * C4;
    if (idx >= total) return;
    int i = idx / C4, c4 = (idx - i * C4) * 4;
    const int* h = &hx[i * 7];
    float4 bv = *(const float4*)&bias[c4];
    size_t stride = (size_t)n * C;
    float4 m = make_float4(-INFINITY, -INFINITY, -INFINITY, -INFINITY);
#pragma unroll 7
    for (int j = 0; j < 7; ++j) {
        const float* pr = &part[(size_t)h[j] * C + c4];
        float4 s = bv;
        for (int z = 0; z < nz; ++z) {
            float4 p = *(const float4*)&pr[z * stride];
            s.x += p.x; s.y += p.y; s.z += p.z; s.w += p.w;
        }
        m.x = fmaxf(m.x, s.x); m.y = fmaxf(m.y, s.y);
        m.z = fmaxf(m.z, s.z); m.w = fmaxf(m.w, s.w);
    }
    m.x = fmaxf(m.x, 0.f); m.y = fmaxf(m.y, 0.f);
    m.z = fmaxf(m.z, 0.f); m.w = fmaxf(m.w, 0.f);
    *(float4*)&out[(size_t)i * C + c4] = m;
}

// ---------------- fused L3: z-reduce + bias + relu + pool + max/mean --------
__global__ __launch_bounds__(256) void pool3_head1_kern(
    const float* __restrict__ part,  // (4, 642, 512)
    const int*   __restrict__ hx,    // (642,7) — first 162 rows used
    const float* __restrict__ bias,  // (512)
    float* __restrict__ xc)          // (1024)
{
    __shared__ float s_mx[4][64], s_sm[4][64];
    const int t = threadIdx.x;
    const int c = blockIdx.x * 64 + (t & 63);
    const int rg = t >> 6;
    const float bv = bias[c];
    const size_t stride = (size_t)642 * 512;
    float mx = -INFINITY, sm = 0.f;
    for (int i = rg; i < 162; i += 4) {
        float m = -INFINITY;
#pragma unroll
        for (int j = 0; j < 7; ++j) {
            int r = hx[i * 7 + j];
            const float* pr = &part[(size_t)r * 512 + c];
            float s = bv + pr[0] + pr[stride] + pr[2 * stride] + pr[3 * stride];
            m = fmaxf(m, s);
        }
        m = fmaxf(m, 0.f);
        mx = fmaxf(mx, m);
        sm += m;
    }
    s_mx[rg][t & 63] = mx; s_sm[rg][t & 63] = sm;
    __syncthreads();
    if (rg == 0) {
#pragma unroll
        for (int q = 1; q < 4; ++q) {
            mx = fmaxf(mx, s_mx[q][t]);
            sm += s_sm[q][t];
        }
        xc[c] = mx;
        xc[512 + c] = sm * (1.f / 162.f);
    }
}

// ---------------- FC head ---------------------------------------------------
__global__ __launch_bounds__(256) void fc1_part_kern(
    const float* __restrict__ xc,   // (1024)
    const float* __restrict__ fcW,  // (1024,512)
    float* __restrict__ partials)   // (8,512)
{
    __shared__ float s_p[4][64];
    const int t = threadIdx.x;
    const int o = blockIdx.x * 64 + (t & 63);
    const int jg = t >> 6;
    const int jbase = blockIdx.y * 128 + jg * 32;
    float acc = 0.f;
#pragma unroll
    for (int jj = 0; jj < 32; ++jj) {
        int j = jbase + jj;
        acc += xc[j] * fcW[j * 512 + o];
    }
    s_p[jg][t & 63] = acc;
    __syncthreads();
    if (jg == 0) {
#pragma unroll
        for (int q = 1; q < 4; ++q) acc += s_p[q][t];
        partials[blockIdx.y * 512 + o] = acc;
    }
}

__global__ __launch_bounds__(512) void head2_kern(
    const float* __restrict__ partials, // (8,512)
    const float* __restrict__ fcb,
    const float* __restrict__ fc2W,
    const float* __restrict__ fc2b,
    float* __restrict__ out)
{
    __shared__ float red[512];
    const int t = threadIdx.x;
    float p = fcb[t];
#pragma unroll
    for (int q = 0; q < 8; ++q) p += partials[q * 512 + t];
    red[t] = fmaxf(p, 0.f) * fc2W[t];
    __syncthreads();
    for (int s = 256; s > 0; s >>= 1) {
        if (t < s) red[t] += red[t + s];
        __syncthreads();
    }
    if (t == 0) out[0] = red[0] + fc2b[0];
}

// ---------------------------------------------------------------------------
extern "C" void kernel_launch(void* const* d_in, const int* in_sizes, int n_in,
                              void* d_out, int out_size, void* d_ws, size_t ws_size,
                              hipStream_t stream)
{
    const float* x0      = (const float*)d_in[0];
    const int*   src6    = (const int*)  d_in[1];
    const float* pseudo6 = (const float*)d_in[3];
    const int*   hex6    = (const int*)  d_in[4];
    const int*   src5    = (const int*)  d_in[5];
    const float* pseudo5 = (const float*)d_in[7];
    const int*   hex5    = (const int*)  d_in[8];
    const int*   src4    = (const int*)  d_in[9];
    const float* pseudo4 = (const float*)d_in[11];
    const int*   hex4    = (const int*)  d_in[12];
    const int*   src3    = (const int*)  d_in[13];
    const float* pseudo3 = (const float*)d_in[15];
    const int*   hex3    = (const int*)  d_in[16];

    const float* g1 = (const float*)d_in[17]; const float* mu1 = (const float*)d_in[18];
    const float* sg1 = (const float*)d_in[19]; const float* rt1 = (const float*)d_in[20];
    const float* b1 = (const float*)d_in[21];
    const float* g2 = (const float*)d_in[22]; const float* mu2 = (const float*)d_in[23];
    const float* sg2 = (const float*)d_in[24]; const float* rt2 = (const float*)d_in[25];
    const float* b2 = (const float*)d_in[26];
    const float* g3 = (const float*)d_in[27]; const float* mu3 = (const float*)d_in[28];
    const float* sg3 = (const float*)d_in[29]; const float* rt3 = (const float*)d_in[30];
    const float* b3 = (const float*)d_in[31];
    const float* g4 = (const float*)d_in[32]; const float* mu4 = (const float*)d_in[33];
    const float* sg4 = (const float*)d_in[34]; const float* rt4 = (const float*)d_in[35];
    const float* b4 = (const float*)d_in[36];
    const float* fcW = (const float*)d_in[37]; const float* fcb = (const float*)d_in[38];
    const float* fc2W = (const float*)d_in[39]; const float* fc2b = (const float*)d_in[40];

    float* out = (float*)d_out;

    float* ws = (float*)d_ws;
    float* A      = ws;             // <= 10242*192 = 1,966,464
    float* CG     = ws + 2000000;   // conv(L6) / z-partials, <= 2,621,952
    float* pooled = ws + 4700000;   // <= 10242*64 = 655,488
    float* xc     = ws + 5400000;   // 1024
    float* fcpart = ws + 5402048;   // 8*512

    // ---- level 6: n=40962, cin=4, cout=64 — fully fused conv ----
    {
        const int n = 40962, cout = 64;
        conv6_fused<<<(n + 63) / 64, 256, 0, stream>>>(
            x0, src6, pseudo6, mu1, sg1, g1, rt1, b1, CG, n);
        int L = 10242, tot = L * cout / 4;
        hexpool_kern<<<(tot + 255) / 256, 256, 0, stream>>>(CG, hex6, pooled, L, cout);
    }
    // ---- level 5: n=10242, cin=64, cout=128 — z=2 split-K ----
    {
        const int n = 10242, cout = 128;
        build_A_kern<64><<<(n + 3) / 4, 256, 0, stream>>>(pooled, src5, pseudo5, mu2, sg2, A, n);
        dim3 grid((n + 63) / 64, cout / 64, 2);
        gemm_node4<2, true><<<grid, 512, 0, stream>>>(A, pooled, g2, rt2, b2, CG, n, 64, cout);
        int L = 2562, tot = L * cout / 4;
        hexpool_reduce_kern<<<(tot + 255) / 256, 256, 0, stream>>>(CG, hex5, b2, pooled, L, cout, n, 2);
    }
    // ---- level 4: n=2562, cin=128, cout=256 — z=2 split-K ----
    {
        const int n = 2562, cout = 256;
        build_A_kern<128><<<(n + 1) / 2, 256, 0, stream>>>(pooled, src4, pseudo4, mu3, sg3, A, n);
        dim3 grid((n + 63) / 64, cout / 64, 2);
        gemm_node4<2, true><<<grid, 512, 0, stream>>>(A, pooled, g3, rt3, b3, CG, n, 128, cout);
        int L = 642, tot = L * cout / 4;
        hexpool_reduce_kern<<<(tot + 255) / 256, 256, 0, stream>>>(CG, hex4, b3, pooled, L, cout, n, 2);
    }
    // ---- level 3: n=642, cin=256, cout=512 — z=4 split-K + fused head1 ----
    {
        const int n = 642, cout = 512;
        build_A_kern<256><<<n, 256, 0, stream>>>(pooled, src3, pseudo3, mu4, sg4, A, n);
        dim3 grid((n + 63) / 64, cout / 64, 4);
        gemm_node4<2, true><<<grid, 512, 0, stream>>>(A, pooled, g4, rt4, b4, CG, n, 256, cout);
        pool3_head1_kern<<<8, 256, 0, stream>>>(CG, hex3, b4, xc);
    }
    // ---- FC head ----
    {
        dim3 grid(8, 8);
        fc1_part_kern<<<grid, 256, 0, stream>>>(xc, fcW, fcpart);
    }
    head2_kern<<<1, 512, 0, stream>>>(fcpart, fcb, fc2W, fc2b, out);
}

// Round 8
// 155.651 us; speedup vs baseline: 1.1844x; 1.1844x over previous
//
#include <hip/hip_runtime.h>
#include <hip/hip_bf16.h>
#include <math.h>

// ---------------------------------------------------------------------------
// MoNet regression on icosphere graphs.
//   * edge_dst = repeat(arange(n), 6)  -> node i owns edges [6i, 6i+6)
//   * hex_pool keeps only first L rows; relu commutes with max-pool
//   * gmm_conv folded to node-level GEMM:
//       A[i, k*cin+c] = (1/6) sum_e w[e,k] * x[src[e], c]
//       out = relu( [A|x] @ [G'|root] + b ),  G'[k*cin+c, o] = g[c, k*cout+o]
// v6: v5 minus the pool3_head1 fusion (8-block serial gather was 55 us at
// 0.3% occupancy — R7 lesson: don't fuse below latency-hiding parallelism).
// L3 tail = wide hexpool_reduce + head1.  14 dispatches.
// ---------------------------------------------------------------------------

#define GEPS 1e-15f

// ---------------- build_A (L5/L4/L3) ---------------------------------------
template <int CIN>
__global__ __launch_bounds__(256) void build_A_kern(
    const float* __restrict__ x,      // (n_src, CIN)
    const int*   __restrict__ src,    // (6n)
    const float* __restrict__ pseudo, // (6n, 3)
    const float* __restrict__ mu,     // (3,3)
    const float* __restrict__ sigma,  // (3,3)
    float* __restrict__ A,            // (n, 3*CIN)
    int n)
{
    constexpr int NB = 256 / CIN;
    constexpr int NE = NB * 6;
    __shared__ float s_w[NE * 3];
    __shared__ int   s_src[NE];
    __shared__ float s_mu[9], s_sig[9];

    const int tid = threadIdx.x;
    if (tid < 9) { s_mu[tid] = mu[tid]; s_sig[tid] = sigma[tid]; }
    __syncthreads();

    const int ebase = blockIdx.x * NE;
    const int nE = n * 6;
    for (int t = tid; t < NE; t += 256) {
        int e = ebase + t;
        if (e < nE) s_src[t] = src[e];
    }
    for (int t = tid; t < NE * 3; t += 256) {
        int e_l = t / 3, k = t - e_l * 3;
        int e = ebase + e_l;
        if (e < nE) {
            float s = 0.f;
#pragma unroll
            for (int d = 0; d < 3; ++d) {
                float diff = pseudo[e * 3 + d] - s_mu[k * 3 + d];
                float sg = s_sig[k * 3 + d];
                s += diff * diff / (sg * sg + GEPS);
            }
            s_w[t] = expf(-0.5f * s);
        }
    }
    __syncthreads();

    const int il = tid / CIN;
    const int c  = tid - il * CIN;
    const int i  = blockIdx.x * NB + il;
    if (i < n) {
        float a0 = 0.f, a1 = 0.f, a2 = 0.f;
#pragma unroll
        for (int e = 0; e < 6; ++e) {
            int s = s_src[il * 6 + e];
            float xv = x[s * CIN + c];
            const float* wp = &s_w[(il * 6 + e) * 3];
            a0 += wp[0] * xv; a1 += wp[1] * xv; a2 += wp[2] * xv;
        }
        const float inv6 = 1.f / 6.f;
        float* Ai = &A[i * (3 * CIN)];
        Ai[0 * CIN + c] = a0 * inv6;
        Ai[1 * CIN + c] = a1 * inv6;
        Ai[2 * CIN + c] = a2 * inv6;
    }
}

// ---------------- fused L6 conv (cin=4, K=16, cout=64) ----------------------
__global__ __launch_bounds__(256) void conv6_fused(
    const float* __restrict__ x,      // (n,4)
    const int*   __restrict__ src,    // (6n)
    const float* __restrict__ pseudo, // (6n,3)
    const float* __restrict__ mu,     // (3,3)
    const float* __restrict__ sigma,  // (3,3)
    const float* __restrict__ g,      // (4,192)
    const float* __restrict__ root,   // (4,64)
    const float* __restrict__ bias,   // (64)
    float* __restrict__ outc,         // (n,64)
    int n)
{
    __shared__ float Bs[16][68];
    __shared__ float xle[64][6][4];
    __shared__ float wle[64][19];
    __shared__ float Als[64][17];

    const int t = threadIdx.x;
    const int node0 = blockIdx.x * 64;
    const int nE = n * 6;

    float muv[9], sgv[9];
#pragma unroll
    for (int q = 0; q < 9; ++q) { muv[q] = mu[q]; sgv[q] = sigma[q]; }

    for (int idx = t; idx < 1024; idx += 256) {
        int jj = idx >> 6, o = idx & 63;
        float v;
        if (jj < 12) { int k = jj >> 2, c = jj & 3; v = g[c * 192 + k * 64 + o]; }
        else v = root[(jj - 12) * 64 + o];
        Bs[jj][o] = v;
    }
    for (int e = t; e < 384; e += 256) {
        int ge = node0 * 6 + e;
        int il = e / 6, el = e - il * 6;
        float4 xv = make_float4(0.f, 0.f, 0.f, 0.f);
        float w0 = 0.f, w1 = 0.f, w2 = 0.f;
        if (ge < nE) {
            xv = *(const float4*)&x[src[ge] * 4];
            float p0 = pseudo[ge * 3 + 0], p1 = pseudo[ge * 3 + 1], p2 = pseudo[ge * 3 + 2];
#pragma unroll
            for (int k = 0; k < 3; ++k) {
                float d0 = p0 - muv[k * 3 + 0], d1 = p1 - muv[k * 3 + 1], d2 = p2 - muv[k * 3 + 2];
                float s0 = sgv[k * 3 + 0], s1 = sgv[k * 3 + 1], s2 = sgv[k * 3 + 2];
                float s = d0 * d0 / (s0 * s0 + GEPS) + d1 * d1 / (s1 * s1 + GEPS)
                        + d2 * d2 / (s2 * s2 + GEPS);
                float w = expf(-0.5f * s);
                if (k == 0) w0 = w; else if (k == 1) w1 = w; else w2 = w;
            }
        }
        *(float4*)&xle[il][el][0] = xv;
        wle[il][el * 3 + 0] = w0; wle[il][el * 3 + 1] = w1; wle[il][el * 3 + 2] = w2;
    }
    if (t < 64) {
        float4 xv = (node0 + t < n) ? *(const float4*)&x[(size_t)(node0 + t) * 4]
                                    : make_float4(0.f, 0.f, 0.f, 0.f);
        Als[t][12] = xv.x; Als[t][13] = xv.y; Als[t][14] = xv.z; Als[t][15] = xv.w;
    }
    __syncthreads();
    for (int ent = t; ent < 768; ent += 256) {
        int il = ent / 12, j = ent - il * 12;
        int k = j >> 2, c = j & 3;
        float a = 0.f;
#pragma unroll
        for (int e = 0; e < 6; ++e)
            a += wle[il][e * 3 + k] * xle[il][e][c];
        Als[il][j] = a * (1.f / 6.f);
    }
    __syncthreads();
    {
        int il = t >> 2, og = (t & 3) * 16;
        if (node0 + il < n) {
            float acc[16];
#pragma unroll
            for (int q = 0; q < 16; ++q) acc[q] = 0.f;
#pragma unroll
            for (int j = 0; j < 16; ++j) {
                float a = Als[il][j];
#pragma unroll
                for (int q = 0; q < 16; ++q)
                    acc[q] += a * Bs[j][og + q];
            }
            float* po = &outc[(size_t)(node0 + il) * 64 + og];
#pragma unroll
            for (int q = 0; q < 16; q += 4) {
                float4 v;
                v.x = fmaxf(acc[q + 0] + bias[og + q + 0], 0.f);
                v.y = fmaxf(acc[q + 1] + bias[og + q + 1], 0.f);
                v.z = fmaxf(acc[q + 2] + bias[og + q + 2], 0.f);
                v.w = fmaxf(acc[q + 3] + bias[og + q + 3], 0.f);
                *(float4*)&po[q] = v;
            }
        }
    }
}

// ---------------- GEMM: 64x64 tile, 4x4 acc, KG in-block + grid.z split-K ---
#define LOAD3(kt)                                                             \
    {                                                                         \
        int jA = k0 + (kt) * 16 + lj;                                         \
        if (gi_l < n) {                                                       \
            ra = (jA < K3) ? *(const float4*)&A[gi_l * K3 + jA]               \
                           : *(const float4*)&x[gi_l * cin + (jA - K3)];      \
        } else { ra = make_float4(0.f, 0.f, 0.f, 0.f); }                      \
        int jB = k0 + (kt) * 16 + lkr;                                        \
        if (jB < K3) {                                                        \
            int kq = jB / cin, c = jB - kq * cin;                             \
            rb = *(const float4*)&g[c * (3 * cout) + kq * cout + bn + lc];    \
        } else {                                                              \
            rb = *(const float4*)&root[(jB - K3) * cout + bn + lc];           \
        }                                                                     \
    }

#define STORE3(b_)                                                            \
    {                                                                         \
        As[grp][b_][lj + 0][lr] = ra.x;                                       \
        As[grp][b_][lj + 1][lr] = ra.y;                                       \
        As[grp][b_][lj + 2][lr] = ra.z;                                       \
        As[grp][b_][lj + 3][lr] = ra.w;                                       \
        *(float4*)&Bs[grp][b_][lkr][lc] = rb;                                 \
    }

template <int KG, bool SPLIT>
__global__ __launch_bounds__(256 * KG) void gemm_node4(
    const float* __restrict__ A,    // (n, 3*cin)
    const float* __restrict__ x,    // (n, cin)
    const float* __restrict__ g,    // (cin, 3*cout)
    const float* __restrict__ root, // (cin, cout)
    const float* __restrict__ bias, // (cout)   (unused when SPLIT)
    float* __restrict__ out,        // (n, cout) or partials (nz, n, cout)
    int n, int cin, int cout)
{
    __shared__ float As[KG][2][16][68];
    __shared__ float Bs[KG][2][16][64];

    const int tid = threadIdx.x;
    const int grp = tid >> 8;
    const int t   = tid & 255;

    const int bm = blockIdx.x * 64;
    const int bn = blockIdx.y * 64;
    const int K3 = 3 * cin;
    const int KK = 4 * cin;
    const int nz = SPLIT ? gridDim.z : 1;
    const int chunk = KK / (nz * KG);
    const int k0 = (blockIdx.z * KG + grp) * chunk;
    const int nkt = chunk >> 4;

    const int lr  = t & 63;
    const int lj  = (t >> 6) * 4;
    const int gi_l = bm + lr;
    const int lkr = t >> 4;
    const int lc  = (t & 15) * 4;

    const int row0 = (t >> 4) * 4;
    const int col0 = (t & 15) * 4;

    float acc[4][4] = {};
    float4 ra, rb;

    LOAD3(0);
    STORE3(0);
    __syncthreads();

    int buf = 0;
    for (int kt = 0; kt < nkt; ++kt) {
        if (kt + 1 < nkt) LOAD3(kt + 1);
#pragma unroll
        for (int kk = 0; kk < 16; ++kk) {
            float4 a = *(const float4*)&As[grp][buf][kk][row0];
            float4 b = *(const float4*)&Bs[grp][buf][kk][col0];
            acc[0][0] += a.x * b.x; acc[0][1] += a.x * b.y;
            acc[0][2] += a.x * b.z; acc[0][3] += a.x * b.w;
            acc[1][0] += a.y * b.x; acc[1][1] += a.y * b.y;
            acc[1][2] += a.y * b.z; acc[1][3] += a.y * b.w;
            acc[2][0] += a.z * b.x; acc[2][1] += a.z * b.y;
            acc[2][2] += a.z * b.z; acc[2][3] += a.z * b.w;
            acc[3][0] += a.w * b.x; acc[3][1] += a.w * b.y;
            acc[3][2] += a.w * b.z; acc[3][3] += a.w * b.w;
        }
        if (kt + 1 < nkt) {
            STORE3(buf ^ 1);
            __syncthreads();
            buf ^= 1;
        }
    }

    __syncthreads();
    float* Rs0 = (float*)As;

#define WRITE_R(R)                                                            \
    {                                                                         \
        _Pragma("unroll")                                                     \
        for (int i2 = 0; i2 < 4; ++i2)                                        \
            *(float4*)&(R)[(row0 + i2) * 64 + col0] =                         \
                make_float4(acc[i2][0], acc[i2][1], acc[i2][2], acc[i2][3]);  \
    }
#define ADD_R(R)                                                              \
    {                                                                         \
        _Pragma("unroll")                                                     \
        for (int i2 = 0; i2 < 4; ++i2) {                                      \
            float4 r = *(const float4*)&(R)[(row0 + i2) * 64 + col0];         \
            acc[i2][0] += r.x; acc[i2][1] += r.y;                             \
            acc[i2][2] += r.z; acc[i2][3] += r.w;                             \
        }                                                                     \
    }

    if constexpr (KG == 2) {
        if (grp == 1) WRITE_R(Rs0);
        __syncthreads();
        if (grp == 0) ADD_R(Rs0);
    }

    if (grp == 0) {
        if constexpr (SPLIT) {
            float* po = &out[(size_t)blockIdx.z * n * cout];
#pragma unroll
            for (int i2 = 0; i2 < 4; ++i2) {
                int gi = bm + row0 + i2;
                if (gi < n)
                    *(float4*)&po[gi * cout + bn + col0] =
                        make_float4(acc[i2][0], acc[i2][1], acc[i2][2], acc[i2][3]);
            }
        } else {
            float4 bv = *(const float4*)&bias[bn + col0];
#pragma unroll
            for (int i2 = 0; i2 < 4; ++i2) {
                int gi = bm + row0 + i2;
                if (gi < n) {
                    float4 v;
                    v.x = fmaxf(acc[i2][0] + bv.x, 0.f);
                    v.y = fmaxf(acc[i2][1] + bv.y, 0.f);
                    v.z = fmaxf(acc[i2][2] + bv.z, 0.f);
                    v.w = fmaxf(acc[i2][3] + bv.w, 0.f);
                    *(float4*)&out[gi * cout + bn + col0] = v;
                }
            }
        }
    }
}

// ---------------- plain hexpool (L6) ----------------------------------------
__global__ void hexpool_kern(const float* __restrict__ xin,
                             const int* __restrict__ hx,
                             float* __restrict__ out, int L, int C)
{
    int idx = blockIdx.x * blockDim.x + threadIdx.x;
    int C4 = C >> 2;
    int total = L * C4;
    if (idx >= total) return;
    int i = idx / C4, c4 = (idx - i * C4) * 4;
    const int* h = &hx[i * 7];
    float4 m = make_float4(-INFINITY, -INFINITY, -INFINITY, -INFINITY);
#pragma unroll
    for (int j = 0; j < 7; ++j) {
        float4 v = *(const float4*)&xin[h[j] * C + c4];
        m.x = fmaxf(m.x, v.x); m.y = fmaxf(m.y, v.y);
        m.z = fmaxf(m.z, v.z); m.w = fmaxf(m.w, v.w);
    }
    *(float4*)&out[i * C + c4] = m;
}

// ---------------- fused z-reduce + bias + relu + hexpool (L5/L4/L3) ---------
__global__ void hexpool_reduce_kern(
    const float* __restrict__ part,  // (nz, n, C)
    const int*   __restrict__ hx,    // (n,7) — first L rows used
    const float* __restrict__ bias,  // (C)
    float* __restrict__ out,         // (L, C)
    int L, int C, int n, int nz)
{
    int idx = blockIdx.x * blockDim.x + threadIdx.x;
    int C4 = C >> 2;
    int total = L * C4;
    if (idx >= total) return;
    int i = idx / C4, c4 = (idx - i * C4) * 4;
    const int* h = &hx[i * 7];
    float4 bv = *(const float4*)&bias[c4];
    size_t stride = (size_t)n * C;
    float4 m = make_float4(-INFINITY, -INFINITY, -INFINITY, -INFINITY);
#pragma unroll 7
    for (int j = 0; j < 7; ++j) {
        const float* pr = &part[(size_t)h[j] * C + c4];
        float4 s = bv;
        for (int z = 0; z < nz; ++z) {
            float4 p = *(const float4*)&pr[z * stride];
            s.x += p.x; s.y += p.y; s.z += p.z; s.w += p.w;
        }
        m.x = fmaxf(m.x, s.x); m.y = fmaxf(m.y, s.y);
        m.z = fmaxf(m.z, s.z); m.w = fmaxf(m.w, s.w);
    }
    m.x = fmaxf(m.x, 0.f); m.y = fmaxf(m.y, 0.f);
    m.z = fmaxf(m.z, 0.f); m.w = fmaxf(m.w, 0.f);
    *(float4*)&out[(size_t)i * C + c4] = m;
}

// ---------------- head ------------------------------------------------------
__global__ __launch_bounds__(256) void head1_kern(const float* __restrict__ xin, // (162,512)
                                                  float* __restrict__ xc)        // (1024)
{
    __shared__ float s_mx[4][64], s_sm[4][64];
    const int t = threadIdx.x;
    const int c = blockIdx.x * 64 + (t & 63);
    const int rg = t >> 6;
    float mx = -INFINITY, sm = 0.f;
    for (int r = rg; r < 162; r += 4) {
        float v = xin[r * 512 + c];
        mx = fmaxf(mx, v);
        sm += v;
    }
    s_mx[rg][t & 63] = mx; s_sm[rg][t & 63] = sm;
    __syncthreads();
    if (rg == 0) {
#pragma unroll
        for (int q = 1; q < 4; ++q) {
            mx = fmaxf(mx, s_mx[q][t]);
            sm += s_sm[q][t];
        }
        xc[c] = mx;
        xc[512 + c] = sm * (1.f / 162.f);
    }
}

__global__ __launch_bounds__(256) void fc1_part_kern(
    const float* __restrict__ xc,   // (1024)
    const float* __restrict__ fcW,  // (1024,512)
    float* __restrict__ partials)   // (8,512)
{
    __shared__ float s_p[4][64];
    const int t = threadIdx.x;
    const int o = blockIdx.x * 64 + (t & 63);
    const int jg = t >> 6;
    const int jbase = blockIdx.y * 128 + jg * 32;
    float acc = 0.f;
#pragma unroll
    for (int jj = 0; jj < 32; ++jj) {
        int j = jbase + jj;
        acc += xc[j] * fcW[j * 512 + o];
    }
    s_p[jg][t & 63] = acc;
    __syncthreads();
    if (jg == 0) {
#pragma unroll
        for (int q = 1; q < 4; ++q) acc += s_p[q][t];
        partials[blockIdx.y * 512 + o] = acc;
    }
}

__global__ __launch_bounds__(512) void head2_kern(
    const float* __restrict__ partials, // (8,512)
    const float* __restrict__ fcb,
    const float* __restrict__ fc2W,
    const float* __restrict__ fc2b,
    float* __restrict__ out)
{
    __shared__ float red[512];
    const int t = threadIdx.x;
    float p = fcb[t];
#pragma unroll
    for (int q = 0; q < 8; ++q) p += partials[q * 512 + t];
    red[t] = fmaxf(p, 0.f) * fc2W[t];
    __syncthreads();
    for (int s = 256; s > 0; s >>= 1) {
        if (t < s) red[t] += red[t + s];
        __syncthreads();
    }
    if (t == 0) out[0] = red[0] + fc2b[0];
}

// ---------------------------------------------------------------------------
extern "C" void kernel_launch(void* const* d_in, const int* in_sizes, int n_in,
                              void* d_out, int out_size, void* d_ws, size_t ws_size,
                              hipStream_t stream)
{
    const float* x0      = (const float*)d_in[0];
    const int*   src6    = (const int*)  d_in[1];
    const float* pseudo6 = (const float*)d_in[3];
    const int*   hex6    = (const int*)  d_in[4];
    const int*   src5    = (const int*)  d_in[5];
    const float* pseudo5 = (const float*)d_in[7];
    const int*   hex5    = (const int*)  d_in[8];
    const int*   src4    = (const int*)  d_in[9];
    const float* pseudo4 = (const float*)d_in[11];
    const int*   hex4    = (const int*)  d_in[12];
    const int*   src3    = (const int*)  d_in[13];
    const float* pseudo3 = (const float*)d_in[15];
    const int*   hex3    = (const int*)  d_in[16];

    const float* g1 = (const float*)d_in[17]; const float* mu1 = (const float*)d_in[18];
    const float* sg1 = (const float*)d_in[19]; const float* rt1 = (const float*)d_in[20];
    const float* b1 = (const float*)d_in[21];
    const float* g2 = (const float*)d_in[22]; const float* mu2 = (const float*)d_in[23];
    const float* sg2 = (const float*)d_in[24]; const float* rt2 = (const float*)d_in[25];
    const float* b2 = (const float*)d_in[26];
    const float* g3 = (const float*)d_in[27]; const float* mu3 = (const float*)d_in[28];
    const float* sg3 = (const float*)d_in[29]; const float* rt3 = (const float*)d_in[30];
    const float* b3 = (const float*)d_in[31];
    const float* g4 = (const float*)d_in[32]; const float* mu4 = (const float*)d_in[33];
    const float* sg4 = (const float*)d_in[34]; const float* rt4 = (const float*)d_in[35];
    const float* b4 = (const float*)d_in[36];
    const float* fcW = (const float*)d_in[37]; const float* fcb = (const float*)d_in[38];
    const float* fc2W = (const float*)d_in[39]; const float* fc2b = (const float*)d_in[40];

    float* out = (float*)d_out;

    float* ws = (float*)d_ws;
    float* A      = ws;             // <= 10242*192 = 1,966,464
    float* CG     = ws + 2000000;   // conv(L6) / z-partials, <= 2,621,952
    float* pooled = ws + 4700000;   // <= 10242*64 = 655,488
    float* xc     = ws + 5400000;   // 1024
    float* fcpart = ws + 5402048;   // 8*512

    // ---- level 6: n=40962, cin=4, cout=64 — fully fused conv ----
    {
        const int n = 40962, cout = 64;
        conv6_fused<<<(n + 63) / 64, 256, 0, stream>>>(
            x0, src6, pseudo6, mu1, sg1, g1, rt1, b1, CG, n);
        int L = 10242, tot = L * cout / 4;
        hexpool_kern<<<(tot + 255) / 256, 256, 0, stream>>>(CG, hex6, pooled, L, cout);
    }
    // ---- level 5: n=10242, cin=64, cout=128 — z=2 split-K ----
    {
        const int n = 10242, cout = 128;
        build_A_kern<64><<<(n + 3) / 4, 256, 0, stream>>>(pooled, src5, pseudo5, mu2, sg2, A, n);
        dim3 grid((n + 63) / 64, cout / 64, 2);
        gemm_node4<2, true><<<grid, 512, 0, stream>>>(A, pooled, g2, rt2, b2, CG, n, 64, cout);
        int L = 2562, tot = L * cout / 4;
        hexpool_reduce_kern<<<(tot + 255) / 256, 256, 0, stream>>>(CG, hex5, b2, pooled, L, cout, n, 2);
    }
    // ---- level 4: n=2562, cin=128, cout=256 — z=2 split-K ----
    {
        const int n = 2562, cout = 256;
        build_A_kern<128><<<(n + 1) / 2, 256, 0, stream>>>(pooled, src4, pseudo4, mu3, sg3, A, n);
        dim3 grid((n + 63) / 64, cout / 64, 2);
        gemm_node4<2, true><<<grid, 512, 0, stream>>>(A, pooled, g3, rt3, b3, CG, n, 128, cout);
        int L = 642, tot = L * cout / 4;
        hexpool_reduce_kern<<<(tot + 255) / 256, 256, 0, stream>>>(CG, hex4, b3, pooled, L, cout, n, 2);
    }
    // ---- level 3: n=642, cin=256, cout=512 — z=4 split-K ----
    {
        const int n = 642, cout = 512;
        build_A_kern<256><<<n, 256, 0, stream>>>(pooled, src3, pseudo3, mu4, sg4, A, n);
        dim3 grid((n + 63) / 64, cout / 64, 4);
        gemm_node4<2, true><<<grid, 512, 0, stream>>>(A, pooled, g4, rt4, b4, CG, n, 256, cout);
        int L = 162, tot = L * cout / 4;
        hexpool_reduce_kern<<<(tot + 255) / 256, 256, 0, stream>>>(CG, hex3, b4, pooled, L, cout, n, 4);
    }
    // ---- head ----
    head1_kern<<<8, 256, 0, stream>>>(pooled, xc);
    {
        dim3 grid(8, 8);
        fc1_part_kern<<<grid, 256, 0, stream>>>(xc, fcW, fcpart);
    }
    head2_kern<<<1, 512, 0, stream>>>(fcpart, fcb, fc2W, fc2b, out);
}

// Round 9
// 135.732 us; speedup vs baseline: 1.3583x; 1.1467x over previous
//
#include <hip/hip_runtime.h>
#include <hip/hip_bf16.h>
#include <math.h>

// ---------------------------------------------------------------------------
// MoNet regression on icosphere graphs.  v7: MFMA GEMMs.
//   * edge_dst = repeat(arange(n), 6) -> node i owns edges [6i,6i+6)
//   * gmm_conv folded:  A[i,k*cin+c] = (1/6) sum_e w[e,k] x[src[e],c]
//       out = relu([A|x] @ [G'|root] + b)
//   * GEMM via mfma_f32_16x16x32_bf16 with f32->bf16 hi/lo 3-term split
//     (rel err ~2^-18/product; ~1e-3 final vs 1.6e-2 threshold).
//     A stored (n,KK) bf16 hi/lo; W stored transposed (cout,KK) hi/lo ->
//     every fragment is a contiguous 16B global load; no LDS, no barriers.
//   * prep_kern = build_A(+x passthrough, bf16 convert) ∪ weight transpose
//     (extra blocks, same dispatch).  grid.z split-K partials + fused
//     reduce+bias+relu+hexpool (R7 lesson: keep tails wide).
// ---------------------------------------------------------------------------

#define GEPS 1e-15f

typedef __attribute__((ext_vector_type(8))) short short8;
typedef __attribute__((ext_vector_type(4))) float f32x4;

__device__ inline void sthl(__hip_bfloat16* H, __hip_bfloat16* L, size_t idx, float v)
{
    __hip_bfloat16 h = __float2bfloat16(v);
    H[idx] = h;
    L[idx] = __float2bfloat16(v - __bfloat162float(h));
}

// ---------------- prep: build [A|x] bf16 hi/lo  +  weight transpose ---------
template <int CIN>
__global__ __launch_bounds__(256) void prep_kern(
    const float* __restrict__ x,      // (n_src, CIN)
    const int*   __restrict__ src,    // (6n)
    const float* __restrict__ pseudo, // (6n, 3)
    const float* __restrict__ mu,     // (3,3)
    const float* __restrict__ sigma,  // (3,3)
    const float* __restrict__ g,      // (CIN, 3*cout)
    const float* __restrict__ root,   // (CIN, cout)
    __hip_bfloat16* __restrict__ Ahi, // (n, KK)
    __hip_bfloat16* __restrict__ Alo,
    __hip_bfloat16* __restrict__ Bthi,// (cout, KK)
    __hip_bfloat16* __restrict__ Btlo,
    int n, int cout, int nbA)
{
    constexpr int KK = 4 * CIN;
    constexpr int K3 = 3 * CIN;

    if ((int)blockIdx.x >= nbA) {
        // ---- weight transpose/convert: W[j][c] -> Bt[c][j] (hi/lo bf16) ----
        int idx0 = (blockIdx.x - nbA) * 256 + threadIdx.x;   // < KK*cout
        int j = idx0 & (KK - 1);
        int c = idx0 / KK;
        float v;
        if (j < K3) {
            int kq = j / CIN, cc = j & (CIN - 1);
            v = g[(size_t)cc * (3 * cout) + (size_t)kq * cout + c];
        } else {
            v = root[(size_t)(j - K3) * cout + c];
        }
        sthl(Bthi, Btlo, (size_t)c * KK + j, v);
        return;
    }

    // ---- build_A ----
    constexpr int NB = 256 / CIN;
    constexpr int NE = NB * 6;
    __shared__ float s_w[NE * 3];
    __shared__ int   s_src[NE];
    __shared__ float s_mu[9], s_sig[9];

    const int tid = threadIdx.x;
    if (tid < 9) { s_mu[tid] = mu[tid]; s_sig[tid] = sigma[tid]; }
    __syncthreads();

    const int ebase = blockIdx.x * NE;
    const int nE = n * 6;
    for (int t = tid; t < NE; t += 256) {
        int e = ebase + t;
        if (e < nE) s_src[t] = src[e];
    }
    for (int t = tid; t < NE * 3; t += 256) {
        int e_l = t / 3, k = t - e_l * 3;
        int e = ebase + e_l;
        if (e < nE) {
            float s = 0.f;
#pragma unroll
            for (int d = 0; d < 3; ++d) {
                float diff = pseudo[e * 3 + d] - s_mu[k * 3 + d];
                float sg = s_sig[k * 3 + d];
                s += diff * diff / (sg * sg + GEPS);
            }
            s_w[t] = expf(-0.5f * s);
        }
    }
    __syncthreads();

    const int il = tid / CIN;
    const int c  = tid - il * CIN;
    const int i  = blockIdx.x * NB + il;
    if (i < n) {
        float a0 = 0.f, a1 = 0.f, a2 = 0.f;
#pragma unroll
        for (int e = 0; e < 6; ++e) {
            int s = s_src[il * 6 + e];
            float xv = x[(size_t)s * CIN + c];
            const float* wp = &s_w[(il * 6 + e) * 3];
            a0 += wp[0] * xv; a1 += wp[1] * xv; a2 += wp[2] * xv;
        }
        const float inv6 = 1.f / 6.f;
        size_t base = (size_t)i * KK;
        sthl(Ahi, Alo, base + 0 * CIN + c, a0 * inv6);
        sthl(Ahi, Alo, base + 1 * CIN + c, a1 * inv6);
        sthl(Ahi, Alo, base + 2 * CIN + c, a2 * inv6);
        sthl(Ahi, Alo, base + 3 * CIN + c, x[(size_t)i * CIN + c]);
    }
}

// ---------------- MFMA GEMM: 64x64 tile, 4 waves x (32x32), split-K z -------
__global__ __launch_bounds__(256, 8) void gemm_mfma(
    const __hip_bfloat16* __restrict__ Ahi,  // (n, KK)
    const __hip_bfloat16* __restrict__ Alo,
    const __hip_bfloat16* __restrict__ Bthi, // (cout, KK)
    const __hip_bfloat16* __restrict__ Btlo,
    float* __restrict__ part,                // (nz, n, cout) raw partials
    int n, int KK, int cout)
{
    const int l  = threadIdx.x & 63;
    const int w  = threadIdx.x >> 6;       // 0..3
    const int wr = w >> 1, wc = w & 1;
    const int bm = blockIdx.x * 64;
    const int bn = blockIdx.y * 64;
    const int KC = KK / gridDim.z;
    const int kbase = blockIdx.z * KC + ((l >> 4) << 3);

    int r0 = bm + wr * 32 + (l & 15);
    int r1 = r0 + 16;
    if (r0 >= n) r0 = n - 1;
    if (r1 >= n) r1 = n - 1;
    const int c0 = bn + wc * 32 + (l & 15);
    const int c1 = c0 + 16;

    const __hip_bfloat16* pA0h = Ahi + (size_t)r0 * KK + kbase;
    const __hip_bfloat16* pA0l = Alo + (size_t)r0 * KK + kbase;
    const __hip_bfloat16* pA1h = Ahi + (size_t)r1 * KK + kbase;
    const __hip_bfloat16* pA1l = Alo + (size_t)r1 * KK + kbase;
    const __hip_bfloat16* pB0h = Bthi + (size_t)c0 * KK + kbase;
    const __hip_bfloat16* pB0l = Btlo + (size_t)c0 * KK + kbase;
    const __hip_bfloat16* pB1h = Bthi + (size_t)c1 * KK + kbase;
    const __hip_bfloat16* pB1l = Btlo + (size_t)c1 * KK + kbase;

    f32x4 acc00 = {0.f, 0.f, 0.f, 0.f}, acc01 = acc00, acc10 = acc00, acc11 = acc00;

    const int steps = KC >> 5;
    for (int ks = 0; ks < steps; ++ks) {
        const int ko = ks * 32;
        short8 ah0 = *(const short8*)(pA0h + ko);
        short8 al0 = *(const short8*)(pA0l + ko);
        short8 ah1 = *(const short8*)(pA1h + ko);
        short8 al1 = *(const short8*)(pA1l + ko);
        short8 bh0 = *(const short8*)(pB0h + ko);
        short8 bl0 = *(const short8*)(pB0l + ko);
        short8 bh1 = *(const short8*)(pB1h + ko);
        short8 bl1 = *(const short8*)(pB1l + ko);

        acc00 = __builtin_amdgcn_mfma_f32_16x16x32_bf16(ah0, bh0, acc00, 0, 0, 0);
        acc01 = __builtin_amdgcn_mfma_f32_16x16x32_bf16(ah0, bh1, acc01, 0, 0, 0);
        acc10 = __builtin_amdgcn_mfma_f32_16x16x32_bf16(ah1, bh0, acc10, 0, 0, 0);
        acc11 = __builtin_amdgcn_mfma_f32_16x16x32_bf16(ah1, bh1, acc11, 0, 0, 0);
        acc00 = __builtin_amdgcn_mfma_f32_16x16x32_bf16(ah0, bl0, acc00, 0, 0, 0);
        acc01 = __builtin_amdgcn_mfma_f32_16x16x32_bf16(ah0, bl1, acc01, 0, 0, 0);
        acc10 = __builtin_amdgcn_mfma_f32_16x16x32_bf16(ah1, bl0, acc10, 0, 0, 0);
        acc11 = __builtin_amdgcn_mfma_f32_16x16x32_bf16(ah1, bl1, acc11, 0, 0, 0);
        acc00 = __builtin_amdgcn_mfma_f32_16x16x32_bf16(al0, bh0, acc00, 0, 0, 0);
        acc01 = __builtin_amdgcn_mfma_f32_16x16x32_bf16(al0, bh1, acc01, 0, 0, 0);
        acc10 = __builtin_amdgcn_mfma_f32_16x16x32_bf16(al1, bh0, acc10, 0, 0, 0);
        acc11 = __builtin_amdgcn_mfma_f32_16x16x32_bf16(al1, bh1, acc11, 0, 0, 0);
    }

    // C/D layout: col = lane&15, row = (lane>>4)*4 + reg  [m89-verified]
    float* po = part + (size_t)blockIdx.z * n * cout;
    const int rb = (l >> 4) << 2;
#define ST_TILE(accv, SR, SC)                                                 \
    {                                                                         \
        int rr = bm + wr * 32 + (SR) * 16 + rb;                               \
        int cc = bn + wc * 32 + (SC) * 16 + (l & 15);                         \
        _Pragma("unroll")                                                     \
        for (int q = 0; q < 4; ++q)                                           \
            if (rr + q < n) po[(size_t)(rr + q) * cout + cc] = accv[q];       \
    }
    ST_TILE(acc00, 0, 0); ST_TILE(acc01, 0, 1);
    ST_TILE(acc10, 1, 0); ST_TILE(acc11, 1, 1);
#undef ST_TILE
}

// ---------------- fused L6 conv (cin=4, K=16, cout=64) ----------------------
__global__ __launch_bounds__(256) void conv6_fused(
    const float* __restrict__ x, const int* __restrict__ src,
    const float* __restrict__ pseudo, const float* __restrict__ mu,
    const float* __restrict__ sigma, const float* __restrict__ g,
    const float* __restrict__ root, const float* __restrict__ bias,
    float* __restrict__ outc, int n)
{
    __shared__ float Bs[16][68];
    __shared__ float xle[64][6][4];
    __shared__ float wle[64][19];
    __shared__ float Als[64][17];

    const int t = threadIdx.x;
    const int node0 = blockIdx.x * 64;
    const int nE = n * 6;

    float muv[9], sgv[9];
#pragma unroll
    for (int q = 0; q < 9; ++q) { muv[q] = mu[q]; sgv[q] = sigma[q]; }

    for (int idx = t; idx < 1024; idx += 256) {
        int jj = idx >> 6, o = idx & 63;
        float v;
        if (jj < 12) { int k = jj >> 2, c = jj & 3; v = g[c * 192 + k * 64 + o]; }
        else v = root[(jj - 12) * 64 + o];
        Bs[jj][o] = v;
    }
    for (int e = t; e < 384; e += 256) {
        int ge = node0 * 6 + e;
        int il = e / 6, el = e - il * 6;
        float4 xv = make_float4(0.f, 0.f, 0.f, 0.f);
        float w0 = 0.f, w1 = 0.f, w2 = 0.f;
        if (ge < nE) {
            xv = *(const float4*)&x[src[ge] * 4];
            float p0 = pseudo[ge * 3 + 0], p1 = pseudo[ge * 3 + 1], p2 = pseudo[ge * 3 + 2];
#pragma unroll
            for (int k = 0; k < 3; ++k) {
                float d0 = p0 - muv[k * 3 + 0], d1 = p1 - muv[k * 3 + 1], d2 = p2 - muv[k * 3 + 2];
                float s0 = sgv[k * 3 + 0], s1 = sgv[k * 3 + 1], s2 = sgv[k * 3 + 2];
                float s = d0 * d0 / (s0 * s0 + GEPS) + d1 * d1 / (s1 * s1 + GEPS)
                        + d2 * d2 / (s2 * s2 + GEPS);
                float wv = expf(-0.5f * s);
                if (k == 0) w0 = wv; else if (k == 1) w1 = wv; else w2 = wv;
            }
        }
        *(float4*)&xle[il][el][0] = xv;
        wle[il][el * 3 + 0] = w0; wle[il][el * 3 + 1] = w1; wle[il][el * 3 + 2] = w2;
    }
    if (t < 64) {
        float4 xv = (node0 + t < n) ? *(const float4*)&x[(size_t)(node0 + t) * 4]
                                    : make_float4(0.f, 0.f, 0.f, 0.f);
        Als[t][12] = xv.x; Als[t][13] = xv.y; Als[t][14] = xv.z; Als[t][15] = xv.w;
    }
    __syncthreads();
    for (int ent = t; ent < 768; ent += 256) {
        int il = ent / 12, j = ent - il * 12;
        int k = j >> 2, c = j & 3;
        float a = 0.f;
#pragma unroll
        for (int e = 0; e < 6; ++e)
            a += wle[il][e * 3 + k] * xle[il][e][c];
        Als[il][j] = a * (1.f / 6.f);
    }
    __syncthreads();
    {
        int il = t >> 2, og = (t & 3) * 16;
        if (node0 + il < n) {
            float acc[16];
#pragma unroll
            for (int q = 0; q < 16; ++q) acc[q] = 0.f;
#pragma unroll
            for (int j = 0; j < 16; ++j) {
                float a = Als[il][j];
#pragma unroll
                for (int q = 0; q < 16; ++q)
                    acc[q] += a * Bs[j][og + q];
            }
            float* po = &outc[(size_t)(node0 + il) * 64 + og];
#pragma unroll
            for (int q = 0; q < 16; q += 4) {
                float4 v;
                v.x = fmaxf(acc[q + 0] + bias[og + q + 0], 0.f);
                v.y = fmaxf(acc[q + 1] + bias[og + q + 1], 0.f);
                v.z = fmaxf(acc[q + 2] + bias[og + q + 2], 0.f);
                v.w = fmaxf(acc[q + 3] + bias[og + q + 3], 0.f);
                *(float4*)&po[q] = v;
            }
        }
    }
}

// ---------------- plain hexpool (L6) ----------------------------------------
__global__ void hexpool_kern(const float* __restrict__ xin,
                             const int* __restrict__ hx,
                             float* __restrict__ out, int L, int C)
{
    int idx = blockIdx.x * blockDim.x + threadIdx.x;
    int C4 = C >> 2;
    int total = L * C4;
    if (idx >= total) return;
    int i = idx / C4, c4 = (idx - i * C4) * 4;
    const int* h = &hx[i * 7];
    float4 m = make_float4(-INFINITY, -INFINITY, -INFINITY, -INFINITY);
#pragma unroll
    for (int j = 0; j < 7; ++j) {
        float4 v = *(const float4*)&xin[h[j] * C + c4];
        m.x = fmaxf(m.x, v.x); m.y = fmaxf(m.y, v.y);
        m.z = fmaxf(m.z, v.z); m.w = fmaxf(m.w, v.w);
    }
    *(float4*)&out[i * C + c4] = m;
}

// ---------------- fused z-reduce + bias + relu + hexpool --------------------
__global__ void hexpool_reduce_kern(
    const float* __restrict__ part,  // (nz, n, C)
    const int*   __restrict__ hx,    // (n,7) — first L rows used
    const float* __restrict__ bias,  // (C)
    float* __restrict__ out,         // (L, C)
    int L, int C, int n, int nz)
{
    int idx = blockIdx.x * blockDim.x + threadIdx.x;
    int C4 = C >> 2;
    int total = L * C4;
    if (idx >= total) return;
    int i = idx / C4, c4 = (idx - i * C4) * 4;
    const int* h = &hx[i * 7];
    float4 bv = *(const float4*)&bias[c4];
    size_t stride = (size_t)n * C;
    float4 m = make_float4(-INFINITY, -INFINITY, -INFINITY, -INFINITY);
#pragma unroll 7
    for (int j = 0; j < 7; ++j) {
        const float* pr = &part[(size_t)h[j] * C + c4];
        float4 s = bv;
        for (int z = 0; z < nz; ++z) {
            float4 p = *(const float4*)&pr[z * stride];
            s.x += p.x; s.y += p.y; s.z += p.z; s.w += p.w;
        }
        m.x = fmaxf(m.x, s.x); m.y = fmaxf(m.y, s.y);
        m.z = fmaxf(m.z, s.z); m.w = fmaxf(m.w, s.w);
    }
    m.x = fmaxf(m.x, 0.f); m.y = fmaxf(m.y, 0.f);
    m.z = fmaxf(m.z, 0.f); m.w = fmaxf(m.w, 0.f);
    *(float4*)&out[(size_t)i * C + c4] = m;
}

// ---------------- head ------------------------------------------------------
__global__ __launch_bounds__(256) void head1_kern(const float* __restrict__ xin, // (162,512)
                                                  float* __restrict__ xc)        // (1024)
{
    __shared__ float s_mx[4][64], s_sm[4][64];
    const int t = threadIdx.x;
    const int c = blockIdx.x * 64 + (t & 63);
    const int rg = t >> 6;
    float mx = -INFINITY, sm = 0.f;
    for (int r = rg; r < 162; r += 4) {
        float v = xin[r * 512 + c];
        mx = fmaxf(mx, v);
        sm += v;
    }
    s_mx[rg][t & 63] = mx; s_sm[rg][t & 63] = sm;
    __syncthreads();
    if (rg == 0) {
#pragma unroll
        for (int q = 1; q < 4; ++q) {
            mx = fmaxf(mx, s_mx[q][t]);
            sm += s_sm[q][t];
        }
        xc[c] = mx;
        xc[512 + c] = sm * (1.f / 162.f);
    }
}

__global__ __launch_bounds__(256) void fc1_part_kern(
    const float* __restrict__ xc, const float* __restrict__ fcW,
    float* __restrict__ partials)
{
    __shared__ float s_p[4][64];
    const int t = threadIdx.x;
    const int o = blockIdx.x * 64 + (t & 63);
    const int jg = t >> 6;
    const int jbase = blockIdx.y * 128 + jg * 32;
    float acc = 0.f;
#pragma unroll
    for (int jj = 0; jj < 32; ++jj) {
        int j = jbase + jj;
        acc += xc[j] * fcW[j * 512 + o];
    }
    s_p[jg][t & 63] = acc;
    __syncthreads();
    if (jg == 0) {
#pragma unroll
        for (int q = 1; q < 4; ++q) acc += s_p[q][t];
        partials[blockIdx.y * 512 + o] = acc;
    }
}

__global__ __launch_bounds__(512) void head2_kern(
    const float* __restrict__ partials, const float* __restrict__ fcb,
    const float* __restrict__ fc2W, const float* __restrict__ fc2b,
    float* __restrict__ out)
{
    __shared__ float red[512];
    const int t = threadIdx.x;
    float p = fcb[t];
#pragma unroll
    for (int q = 0; q < 8; ++q) p += partials[q * 512 + t];
    red[t] = fmaxf(p, 0.f) * fc2W[t];
    __syncthreads();
    for (int s = 256; s > 0; s >>= 1) {
        if (t < s) red[t] += red[t + s];
        __syncthreads();
    }
    if (t == 0) out[0] = red[0] + fc2b[0];
}

// ---------------------------------------------------------------------------
extern "C" void kernel_launch(void* const* d_in, const int* in_sizes, int n_in,
                              void* d_out, int out_size, void* d_ws, size_t ws_size,
                              hipStream_t stream)
{
    const float* x0      = (const float*)d_in[0];
    const int*   src6    = (const int*)  d_in[1];
    const float* pseudo6 = (const float*)d_in[3];
    const int*   hex6    = (const int*)  d_in[4];
    const int*   src5    = (const int*)  d_in[5];
    const float* pseudo5 = (const float*)d_in[7];
    const int*   hex5    = (const int*)  d_in[8];
    const int*   src4    = (const int*)  d_in[9];
    const float* pseudo4 = (const float*)d_in[11];
    const int*   hex4    = (const int*)  d_in[12];
    const int*   src3    = (const int*)  d_in[13];
    const float* pseudo3 = (const float*)d_in[15];
    const int*   hex3    = (const int*)  d_in[16];

    const float* g1 = (const float*)d_in[17]; const float* mu1 = (const float*)d_in[18];
    const float* sg1 = (const float*)d_in[19]; const float* rt1 = (const float*)d_in[20];
    const float* b1 = (const float*)d_in[21];
    const float* g2 = (const float*)d_in[22]; const float* mu2 = (const float*)d_in[23];
    const float* sg2 = (const float*)d_in[24]; const float* rt2 = (const float*)d_in[25];
    const float* b2 = (const float*)d_in[26];
    const float* g3 = (const float*)d_in[27]; const float* mu3 = (const float*)d_in[28];
    const float* sg3 = (const float*)d_in[29]; const float* rt3 = (const float*)d_in[30];
    const float* b3 = (const float*)d_in[31];
    const float* g4 = (const float*)d_in[32]; const float* mu4 = (const float*)d_in[33];
    const float* sg4 = (const float*)d_in[34]; const float* rt4 = (const float*)d_in[35];
    const float* b4 = (const float*)d_in[36];
    const float* fcW = (const float*)d_in[37]; const float* fcb = (const float*)d_in[38];
    const float* fc2W = (const float*)d_in[39]; const float* fc2b = (const float*)d_in[40];

    float* out = (float*)d_out;

    const size_t MB = 1u << 20;
    char* wb = (char*)d_ws;
    __hip_bfloat16* Ahi  = (__hip_bfloat16*)(wb + 0 * MB);   // <= 5.25 MB
    __hip_bfloat16* Alo  = (__hip_bfloat16*)(wb + 6 * MB);   // <= 5.25 MB
    __hip_bfloat16* Bthi = (__hip_bfloat16*)(wb + 12 * MB);  // <= 1 MB
    __hip_bfloat16* Btlo = (__hip_bfloat16*)(wb + 14 * MB);  // <= 1 MB
    float* CG     = (float*)(wb + 16 * MB);                  // conv6 out / partials, <= 10.5 MB
    float* pooled = (float*)(wb + 28 * MB);                  // <= 2.62 MB
    float* xc     = (float*)(wb + 31 * MB);                  // 1024
    float* fcpart = (float*)(wb + 31 * MB + 8192);           // 8*512

    // ---- level 6: n=40962, cin=4, cout=64 — fused f32 conv ----
    {
        const int n = 40962, cout = 64;
        conv6_fused<<<(n + 63) / 64, 256, 0, stream>>>(
            x0, src6, pseudo6, mu1, sg1, g1, rt1, b1, CG, n);
        int L = 10242, tot = L * cout / 4;
        hexpool_kern<<<(tot + 255) / 256, 256, 0, stream>>>(CG, hex6, pooled, L, cout);
    }
    // ---- level 5: n=10242, cin=64, cout=128 — MFMA, z=2 ----
    {
        const int n = 10242, cout = 128, KK = 256;
        int nbA = (n + 3) / 4, nbW = KK * cout / 256;
        prep_kern<64><<<nbA + nbW, 256, 0, stream>>>(
            pooled, src5, pseudo5, mu2, sg2, g2, rt2, Ahi, Alo, Bthi, Btlo, n, cout, nbA);
        dim3 grid((n + 63) / 64, cout / 64, 2);
        gemm_mfma<<<grid, 256, 0, stream>>>(Ahi, Alo, Bthi, Btlo, CG, n, KK, cout);
        int L = 2562, tot = L * cout / 4;
        hexpool_reduce_kern<<<(tot + 255) / 256, 256, 0, stream>>>(CG, hex5, b2, pooled, L, cout, n, 2);
    }
    // ---- level 4: n=2562, cin=128, cout=256 — MFMA, z=2 ----
    {
        const int n = 2562, cout = 256, KK = 512;
        int nbA = (n + 1) / 2, nbW = KK * cout / 256;
        prep_kern<128><<<nbA + nbW, 256, 0, stream>>>(
            pooled, src4, pseudo4, mu3, sg3, g3, rt3, Ahi, Alo, Bthi, Btlo, n, cout, nbA);
        dim3 grid((n + 63) / 64, cout / 64, 2);
        gemm_mfma<<<grid, 256, 0, stream>>>(Ahi, Alo, Bthi, Btlo, CG, n, KK, cout);
        int L = 642, tot = L * cout / 4;
        hexpool_reduce_kern<<<(tot + 255) / 256, 256, 0, stream>>>(CG, hex4, b3, pooled, L, cout, n, 2);
    }
    // ---- level 3: n=642, cin=256, cout=512 — MFMA, z=4 ----
    {
        const int n = 642, cout = 512, KK = 1024;
        int nbA = n, nbW = KK * cout / 256;
        prep_kern<256><<<nbA + nbW, 256, 0, stream>>>(
            pooled, src3, pseudo3, mu4, sg4, g4, rt4, Ahi, Alo, Bthi, Btlo, n, cout, nbA);
        dim3 grid((n + 63) / 64, cout / 64, 4);
        gemm_mfma<<<grid, 256, 0, stream>>>(Ahi, Alo, Bthi, Btlo, CG, n, KK, cout);
        int L = 162, tot = L * cout / 4;
        hexpool_reduce_kern<<<(tot + 255) / 256, 256, 0, stream>>>(CG, hex3, b4, pooled, L, cout, n, 4);
    }
    // ---- head ----
    head1_kern<<<8, 256, 0, stream>>>(pooled, xc);
    {
        dim3 grid(8, 8);
        fc1_part_kern<<<grid, 256, 0, stream>>>(xc, fcW, fcpart);
    }
    head2_kern<<<1, 512, 0, stream>>>(fcpart, fcb, fc2W, fc2b, out);
}

// Round 10
// 129.920 us; speedup vs baseline: 1.4190x; 1.0447x over previous
//
#include <hip/hip_runtime.h>
#include <hip/hip_bf16.h>
#include <math.h>

// ---------------------------------------------------------------------------
// MoNet regression on icosphere graphs.  v8.
//   * edge_dst = repeat(arange(n), 6) -> node i owns edges [6i,6i+6)
//   * gmm_conv folded:  A[i,k*cin+c] = (1/6) sum_e w[e,k] x[src[e],c]
//       out = relu([A|x] @ [G'|root] + b)
//   * L6: conv+hexpool fused (conv6pool) — computes conv for each coarse
//     node's 7 neighbors (1.75x redundant, trivial FLOPs) and pools in-LDS;
//     saves the 10.5MB conv write + 18MB gather re-read + one dispatch.
//   * L5/L4/L3: prep (build_A bf16 hi/lo + weight transpose, one dispatch)
//     -> gemm_mfma (16x16x32 bf16, 3-term hi/lo split, no LDS) with grid.z
//     split-K -> fused z-reduce+bias+relu+hexpool.   13 dispatches.
//   * R4 lesson: never cap VGPRs below need (launch_bounds 2nd arg).
//   * R7 lesson: keep reduction tails wide (no 8-block serial gathers).
// ---------------------------------------------------------------------------

#define GEPS 1e-15f

typedef __attribute__((ext_vector_type(8))) short short8;
typedef __attribute__((ext_vector_type(4))) float f32x4;

__device__ inline void sthl(__hip_bfloat16* H, __hip_bfloat16* L, size_t idx, float v)
{
    __hip_bfloat16 h = __float2bfloat16(v);
    H[idx] = h;
    L[idx] = __float2bfloat16(v - __bfloat162float(h));
}

// ---------------- prep: build [A|x] bf16 hi/lo  +  weight transpose ---------
template <int CIN>
__global__ __launch_bounds__(256) void prep_kern(
    const float* __restrict__ x,      // (n_src, CIN)
    const int*   __restrict__ src,    // (6n)
    const float* __restrict__ pseudo, // (6n, 3)
    const float* __restrict__ mu,     // (3,3)
    const float* __restrict__ sigma,  // (3,3)
    const float* __restrict__ g,      // (CIN, 3*cout)
    const float* __restrict__ root,   // (CIN, cout)
    __hip_bfloat16* __restrict__ Ahi, // (n, KK)
    __hip_bfloat16* __restrict__ Alo,
    __hip_bfloat16* __restrict__ Bthi,// (cout, KK)
    __hip_bfloat16* __restrict__ Btlo,
    int n, int cout, int nbA)
{
    constexpr int KK = 4 * CIN;
    constexpr int K3 = 3 * CIN;

    if ((int)blockIdx.x >= nbA) {
        int idx0 = (blockIdx.x - nbA) * 256 + threadIdx.x;   // < KK*cout
        int j = idx0 & (KK - 1);
        int c = idx0 / KK;
        float v;
        if (j < K3) {
            int kq = j / CIN, cc = j & (CIN - 1);
            v = g[(size_t)cc * (3 * cout) + (size_t)kq * cout + c];
        } else {
            v = root[(size_t)(j - K3) * cout + c];
        }
        sthl(Bthi, Btlo, (size_t)c * KK + j, v);
        return;
    }

    constexpr int NB = 256 / CIN;
    constexpr int NE = NB * 6;
    __shared__ float s_w[NE * 3];
    __shared__ int   s_src[NE];
    __shared__ float s_mu[9], s_sig[9];

    const int tid = threadIdx.x;
    if (tid < 9) { s_mu[tid] = mu[tid]; s_sig[tid] = sigma[tid]; }
    __syncthreads();

    const int ebase = blockIdx.x * NE;
    const int nE = n * 6;
    for (int t = tid; t < NE; t += 256) {
        int e = ebase + t;
        if (e < nE) s_src[t] = src[e];
    }
    for (int t = tid; t < NE * 3; t += 256) {
        int e_l = t / 3, k = t - e_l * 3;
        int e = ebase + e_l;
        if (e < nE) {
            float s = 0.f;
#pragma unroll
            for (int d = 0; d < 3; ++d) {
                float diff = pseudo[e * 3 + d] - s_mu[k * 3 + d];
                float sg = s_sig[k * 3 + d];
                s += diff * diff / (sg * sg + GEPS);
            }
            s_w[t] = expf(-0.5f * s);
        }
    }
    __syncthreads();

    const int il = tid / CIN;
    const int c  = tid - il * CIN;
    const int i  = blockIdx.x * NB + il;
    if (i < n) {
        float a0 = 0.f, a1 = 0.f, a2 = 0.f;
#pragma unroll
        for (int e = 0; e < 6; ++e) {
            int s = s_src[il * 6 + e];
            float xv = x[(size_t)s * CIN + c];
            const float* wp = &s_w[(il * 6 + e) * 3];
            a0 += wp[0] * xv; a1 += wp[1] * xv; a2 += wp[2] * xv;
        }
        const float inv6 = 1.f / 6.f;
        size_t base = (size_t)i * KK;
        sthl(Ahi, Alo, base + 0 * CIN + c, a0 * inv6);
        sthl(Ahi, Alo, base + 1 * CIN + c, a1 * inv6);
        sthl(Ahi, Alo, base + 2 * CIN + c, a2 * inv6);
        sthl(Ahi, Alo, base + 3 * CIN + c, x[(size_t)i * CIN + c]);
    }
}

// ---------------- MFMA GEMM: 64x64 tile, 4 waves x (32x32), split-K z -------
__global__ __launch_bounds__(256) void gemm_mfma(
    const __hip_bfloat16* __restrict__ Ahi,  // (n, KK)
    const __hip_bfloat16* __restrict__ Alo,
    const __hip_bfloat16* __restrict__ Bthi, // (cout, KK)
    const __hip_bfloat16* __restrict__ Btlo,
    float* __restrict__ part,                // (nz, n, cout) raw partials
    int n, int KK, int cout)
{
    const int l  = threadIdx.x & 63;
    const int w  = threadIdx.x >> 6;       // 0..3
    const int wr = w >> 1, wc = w & 1;
    const int bm = blockIdx.x * 64;
    const int bn = blockIdx.y * 64;
    const int KC = KK / gridDim.z;
    const int kbase = blockIdx.z * KC + ((l >> 4) << 3);

    int r0 = bm + wr * 32 + (l & 15);
    int r1 = r0 + 16;
    if (r0 >= n) r0 = n - 1;
    if (r1 >= n) r1 = n - 1;
    const int c0 = bn + wc * 32 + (l & 15);
    const int c1 = c0 + 16;

    const __hip_bfloat16* pA0h = Ahi + (size_t)r0 * KK + kbase;
    const __hip_bfloat16* pA0l = Alo + (size_t)r0 * KK + kbase;
    const __hip_bfloat16* pA1h = Ahi + (size_t)r1 * KK + kbase;
    const __hip_bfloat16* pA1l = Alo + (size_t)r1 * KK + kbase;
    const __hip_bfloat16* pB0h = Bthi + (size_t)c0 * KK + kbase;
    const __hip_bfloat16* pB0l = Btlo + (size_t)c0 * KK + kbase;
    const __hip_bfloat16* pB1h = Bthi + (size_t)c1 * KK + kbase;
    const __hip_bfloat16* pB1l = Btlo + (size_t)c1 * KK + kbase;

    f32x4 acc00 = {0.f, 0.f, 0.f, 0.f}, acc01 = acc00, acc10 = acc00, acc11 = acc00;

    const int steps = KC >> 5;
    for (int ks = 0; ks < steps; ++ks) {
        const int ko = ks * 32;
        short8 ah0 = *(const short8*)(pA0h + ko);
        short8 al0 = *(const short8*)(pA0l + ko);
        short8 ah1 = *(const short8*)(pA1h + ko);
        short8 al1 = *(const short8*)(pA1l + ko);
        short8 bh0 = *(const short8*)(pB0h + ko);
        short8 bl0 = *(const short8*)(pB0l + ko);
        short8 bh1 = *(const short8*)(pB1h + ko);
        short8 bl1 = *(const short8*)(pB1l + ko);

        acc00 = __builtin_amdgcn_mfma_f32_16x16x32_bf16(ah0, bh0, acc00, 0, 0, 0);
        acc01 = __builtin_amdgcn_mfma_f32_16x16x32_bf16(ah0, bh1, acc01, 0, 0, 0);
        acc10 = __builtin_amdgcn_mfma_f32_16x16x32_bf16(ah1, bh0, acc10, 0, 0, 0);
        acc11 = __builtin_amdgcn_mfma_f32_16x16x32_bf16(ah1, bh1, acc11, 0, 0, 0);
        acc00 = __builtin_amdgcn_mfma_f32_16x16x32_bf16(ah0, bl0, acc00, 0, 0, 0);
        acc01 = __builtin_amdgcn_mfma_f32_16x16x32_bf16(ah0, bl1, acc01, 0, 0, 0);
        acc10 = __builtin_amdgcn_mfma_f32_16x16x32_bf16(ah1, bl0, acc10, 0, 0, 0);
        acc11 = __builtin_amdgcn_mfma_f32_16x16x32_bf16(ah1, bl1, acc11, 0, 0, 0);
        acc00 = __builtin_amdgcn_mfma_f32_16x16x32_bf16(al0, bh0, acc00, 0, 0, 0);
        acc01 = __builtin_amdgcn_mfma_f32_16x16x32_bf16(al0, bh1, acc01, 0, 0, 0);
        acc10 = __builtin_amdgcn_mfma_f32_16x16x32_bf16(al1, bh0, acc10, 0, 0, 0);
        acc11 = __builtin_amdgcn_mfma_f32_16x16x32_bf16(al1, bh1, acc11, 0, 0, 0);
    }

    // C/D layout: col = lane&15, row = (lane>>4)*4 + reg  [m89-verified]
    float* po = part + (size_t)blockIdx.z * n * cout;
    const int rb = (l >> 4) << 2;
#define ST_TILE(accv, SR, SC)                                                 \
    {                                                                         \
        int rr = bm + wr * 32 + (SR) * 16 + rb;                               \
        int cc = bn + wc * 32 + (SC) * 16 + (l & 15);                         \
        _Pragma("unroll")                                                     \
        for (int q = 0; q < 4; ++q)                                           \
            if (rr + q < n) po[(size_t)(rr + q) * cout + cc] = accv[q];       \
    }
    ST_TILE(acc00, 0, 0); ST_TILE(acc01, 0, 1);
    ST_TILE(acc10, 1, 0); ST_TILE(acc11, 1, 1);
#undef ST_TILE
}

// ---------------- fused L6 conv + hexpool (cin=4, K=16, cout=64) ------------
// For each coarse node i<L: pooled[i][c] = relu(max_j gmm[hex[i][j]][c] + b[c])
#define NCO 16
__global__ __launch_bounds__(256) void conv6pool(
    const float* __restrict__ x,      // (n,4)
    const int*   __restrict__ src,    // (6n)
    const float* __restrict__ pseudo, // (6n,3)
    const float* __restrict__ mu,     // (3,3)
    const float* __restrict__ sigma,  // (3,3)
    const float* __restrict__ g,      // (4,192)
    const float* __restrict__ root,   // (4,64)
    const float* __restrict__ bias,   // (64)
    const int*   __restrict__ hx,     // (n,7), first L rows used
    float* __restrict__ pooled,       // (L,64)
    int n, int L)
{
    __shared__ float Bs[16][68];          // weight tile [A-rows|x-rows]
    __shared__ int   hlist[NCO * 7];      // fine-node ids (112)
    __shared__ float xle[NCO * 7][6][4];  // gathered neighbor feats
    __shared__ float wle[NCO * 7][18];    // 6 edges x 3 kernels
    __shared__ float Als[NCO * 7][20];    // [A(12)|x(4)|pad] (80B rows, b128-ok)

    const int t = threadIdx.x;
    const int i0 = blockIdx.x * NCO;

    float muv[9], sgv[9];
#pragma unroll
    for (int q = 0; q < 9; ++q) { muv[q] = mu[q]; sgv[q] = sigma[q]; }

    // stage B: rows 0..11 = G'[k*4+c][o], rows 12..15 = root
    for (int idx = t; idx < 1024; idx += 256) {
        int jj = idx >> 6, o = idx & 63;
        float v;
        if (jj < 12) { int k = jj >> 2, c = jj & 3; v = g[c * 192 + k * 64 + o]; }
        else v = root[(jj - 12) * 64 + o];
        Bs[jj][o] = v;
    }
    // hex membership list
    if (t < NCO * 7) {
        int i = i0 + t / 7;
        hlist[t] = (i < L) ? hx[i * 7 + (t - (t / 7) * 7)] : 0;
    }
    __syncthreads();

    // edges: 672 = 112 fine nodes x 6
    for (int e = t; e < NCO * 7 * 6; e += 256) {
        int f = e / 6, el = e - f * 6;
        int ge = hlist[f] * 6 + el;
        float4 xv = *(const float4*)&x[(size_t)src[ge] * 4];
        float p0 = pseudo[ge * 3 + 0], p1 = pseudo[ge * 3 + 1], p2 = pseudo[ge * 3 + 2];
        float w0, w1, w2;
#pragma unroll
        for (int k = 0; k < 3; ++k) {
            float d0 = p0 - muv[k * 3 + 0], d1 = p1 - muv[k * 3 + 1], d2 = p2 - muv[k * 3 + 2];
            float s0 = sgv[k * 3 + 0], s1 = sgv[k * 3 + 1], s2 = sgv[k * 3 + 2];
            float s = d0 * d0 / (s0 * s0 + GEPS) + d1 * d1 / (s1 * s1 + GEPS)
                    + d2 * d2 / (s2 * s2 + GEPS);
            float wv = expf(-0.5f * s);
            if (k == 0) w0 = wv; else if (k == 1) w1 = wv; else w2 = wv;
        }
        *(float4*)&xle[f][el][0] = xv;
        wle[f][el * 3 + 0] = w0; wle[f][el * 3 + 1] = w1; wle[f][el * 3 + 2] = w2;
    }
    __syncthreads();

    // A entries: 112 x 12, plus own-x rows 12..15
    for (int ent = t; ent < NCO * 7 * 12; ent += 256) {
        int f = ent / 12, j = ent - f * 12;
        int k = j >> 2, c = j & 3;
        float a = 0.f;
#pragma unroll
        for (int e = 0; e < 6; ++e)
            a += wle[f][e * 3 + k] * xle[f][e][c];
        Als[f][j] = a * (1.f / 6.f);
    }
    for (int ent = t; ent < NCO * 7 * 4; ent += 256) {
        int f = ent >> 2, d = ent & 3;
        Als[f][12 + d] = x[(size_t)hlist[f] * 4 + d];
    }
    __syncthreads();

    // output: thread owns channel c = t&63, coarse nodes (t>>6)*4 + q
    {
        const int c = t & 63;
        float breg[16];
#pragma unroll
        for (int k = 0; k < 16; ++k) breg[k] = Bs[k][c];
        const float bv = bias[c];
#pragma unroll
        for (int q = 0; q < 4; ++q) {
            int co = (t >> 6) * 4 + q;
            int i = i0 + co;
            if (i < L) {
                float m = -INFINITY;
#pragma unroll
                for (int j = 0; j < 7; ++j) {
                    const float* af = &Als[co * 7 + j][0];
                    float4 a0 = *(const float4*)&af[0];
                    float4 a1 = *(const float4*)&af[4];
                    float4 a2 = *(const float4*)&af[8];
                    float4 a3 = *(const float4*)&af[12];
                    float d = a0.x * breg[0] + a0.y * breg[1] + a0.z * breg[2] + a0.w * breg[3]
                            + a1.x * breg[4] + a1.y * breg[5] + a1.z * breg[6] + a1.w * breg[7]
                            + a2.x * breg[8] + a2.y * breg[9] + a2.z * breg[10] + a2.w * breg[11]
                            + a3.x * breg[12] + a3.y * breg[13] + a3.z * breg[14] + a3.w * breg[15];
                    m = fmaxf(m, d);
                }
                pooled[(size_t)i * 64 + c] = fmaxf(m + bv, 0.f);
            }
        }
    }
}

// ---------------- fused z-reduce + bias + relu + hexpool --------------------
__global__ void hexpool_reduce_kern(
    const float* __restrict__ part,  // (nz, n, C)
    const int*   __restrict__ hx,    // (n,7) — first L rows used
    const float* __restrict__ bias,  // (C)
    float* __restrict__ out,         // (L, C)
    int L, int C, int n, int nz)
{
    int idx = blockIdx.x * blockDim.x + threadIdx.x;
    int C4 = C >> 2;
    int total = L * C4;
    if (idx >= total) return;
    int i = idx / C4, c4 = (idx - i * C4) * 4;
    const int* h = &hx[i * 7];
    float4 bv = *(const float4*)&bias[c4];
    size_t stride = (size_t)n * C;
    float4 m = make_float4(-INFINITY, -INFINITY, -INFINITY, -INFINITY);
#pragma unroll 7
    for (int j = 0; j < 7; ++j) {
        const float* pr = &part[(size_t)h[j] * C + c4];
        float4 s = bv;
        for (int z = 0; z < nz; ++z) {
            float4 p = *(const float4*)&pr[z * stride];
            s.x += p.x; s.y += p.y; s.z += p.z; s.w += p.w;
        }
        m.x = fmaxf(m.x, s.x); m.y = fmaxf(m.y, s.y);
        m.z = fmaxf(m.z, s.z); m.w = fmaxf(m.w, s.w);
    }
    m.x = fmaxf(m.x, 0.f); m.y = fmaxf(m.y, 0.f);
    m.z = fmaxf(m.z, 0.f); m.w = fmaxf(m.w, 0.f);
    *(float4*)&out[(size_t)i * C + c4] = m;
}

// ---------------- head ------------------------------------------------------
__global__ __launch_bounds__(256) void head1_kern(const float* __restrict__ xin, // (162,512)
                                                  float* __restrict__ xc)        // (1024)
{
    __shared__ float s_mx[4][64], s_sm[4][64];
    const int t = threadIdx.x;
    const int c = blockIdx.x * 64 + (t & 63);
    const int rg = t >> 6;
    float mx = -INFINITY, sm = 0.f;
    for (int r = rg; r < 162; r += 4) {
        float v = xin[r * 512 + c];
        mx = fmaxf(mx, v);
        sm += v;
    }
    s_mx[rg][t & 63] = mx; s_sm[rg][t & 63] = sm;
    __syncthreads();
    if (rg == 0) {
#pragma unroll
        for (int q = 1; q < 4; ++q) {
            mx = fmaxf(mx, s_mx[q][t]);
            sm += s_sm[q][t];
        }
        xc[c] = mx;
        xc[512 + c] = sm * (1.f / 162.f);
    }
}

__global__ __launch_bounds__(256) void fc1_part_kern(
    const float* __restrict__ xc, const float* __restrict__ fcW,
    float* __restrict__ partials)
{
    __shared__ float s_p[4][64];
    const int t = threadIdx.x;
    const int o = blockIdx.x * 64 + (t & 63);
    const int jg = t >> 6;
    const int jbase = blockIdx.y * 128 + jg * 32;
    float acc = 0.f;
#pragma unroll
    for (int jj = 0; jj < 32; ++jj) {
        int j = jbase + jj;
        acc += xc[j] * fcW[j * 512 + o];
    }
    s_p[jg][t & 63] = acc;
    __syncthreads();
    if (jg == 0) {
#pragma unroll
        for (int q = 1; q < 4; ++q) acc += s_p[q][t];
        partials[blockIdx.y * 512 + o] = acc;
    }
}

__global__ __launch_bounds__(512) void head2_kern(
    const float* __restrict__ partials, const float* __restrict__ fcb,
    const float* __restrict__ fc2W, const float* __restrict__ fc2b,
    float* __restrict__ out)
{
    __shared__ float red[512];
    const int t = threadIdx.x;
    float p = fcb[t];
#pragma unroll
    for (int q = 0; q < 8; ++q) p += partials[q * 512 + t];
    red[t] = fmaxf(p, 0.f) * fc2W[t];
    __syncthreads();
    for (int s = 256; s > 0; s >>= 1) {
        if (t < s) red[t] += red[t + s];
        __syncthreads();
    }
    if (t == 0) out[0] = red[0] + fc2b[0];
}

// ---------------------------------------------------------------------------
extern "C" void kernel_launch(void* const* d_in, const int* in_sizes, int n_in,
                              void* d_out, int out_size, void* d_ws, size_t ws_size,
                              hipStream_t stream)
{
    const float* x0      = (const float*)d_in[0];
    const int*   src6    = (const int*)  d_in[1];
    const float* pseudo6 = (const float*)d_in[3];
    const int*   hex6    = (const int*)  d_in[4];
    const int*   src5    = (const int*)  d_in[5];
    const float* pseudo5 = (const float*)d_in[7];
    const int*   hex5    = (const int*)  d_in[8];
    const int*   src4    = (const int*)  d_in[9];
    const float* pseudo4 = (const float*)d_in[11];
    const int*   hex4    = (const int*)  d_in[12];
    const int*   src3    = (const int*)  d_in[13];
    const float* pseudo3 = (const float*)d_in[15];
    const int*   hex3    = (const int*)  d_in[16];

    const float* g1 = (const float*)d_in[17]; const float* mu1 = (const float*)d_in[18];
    const float* sg1 = (const float*)d_in[19]; const float* rt1 = (const float*)d_in[20];
    const float* b1 = (const float*)d_in[21];
    const float* g2 = (const float*)d_in[22]; const float* mu2 = (const float*)d_in[23];
    const float* sg2 = (const float*)d_in[24]; const float* rt2 = (const float*)d_in[25];
    const float* b2 = (const float*)d_in[26];
    const float* g3 = (const float*)d_in[27]; const float* mu3 = (const float*)d_in[28];
    const float* sg3 = (const float*)d_in[29]; const float* rt3 = (const float*)d_in[30];
    const float* b3 = (const float*)d_in[31];
    const float* g4 = (const float*)d_in[32]; const float* mu4 = (const float*)d_in[33];
    const float* sg4 = (const float*)d_in[34]; const float* rt4 = (const float*)d_in[35];
    const float* b4 = (const float*)d_in[36];
    const float* fcW = (const float*)d_in[37]; const float* fcb = (const float*)d_in[38];
    const float* fc2W = (const float*)d_in[39]; const float* fc2b = (const float*)d_in[40];

    float* out = (float*)d_out;

    const size_t MB = 1u << 20;
    char* wb = (char*)d_ws;
    __hip_bfloat16* Ahi  = (__hip_bfloat16*)(wb + 0 * MB);   // <= 5.25 MB
    __hip_bfloat16* Alo  = (__hip_bfloat16*)(wb + 6 * MB);   // <= 5.25 MB
    __hip_bfloat16* Bthi = (__hip_bfloat16*)(wb + 12 * MB);  // <= 1 MB
    __hip_bfloat16* Btlo = (__hip_bfloat16*)(wb + 14 * MB);  // <= 1 MB
    float* CG     = (float*)(wb + 16 * MB);                  // z-partials, <= 10.5 MB
    float* pooled = (float*)(wb + 28 * MB);                  // <= 2.62 MB
    float* xc     = (float*)(wb + 31 * MB);                  // 1024
    float* fcpart = (float*)(wb + 31 * MB + 8192);           // 8*512

    // ---- level 6: n=40962, cin=4, cout=64 — fused conv+pool ----
    {
        const int n = 40962, L = 10242;
        conv6pool<<<(L + NCO - 1) / NCO, 256, 0, stream>>>(
            x0, src6, pseudo6, mu1, sg1, g1, rt1, b1, hex6, pooled, n, L);
    }
    // ---- level 5: n=10242, cin=64, cout=128 — MFMA, z=2 ----
    {
        const int n = 10242, cout = 128, KK = 256;
        int nbA = (n + 3) / 4, nbW = KK * cout / 256;
        prep_kern<64><<<nbA + nbW, 256, 0, stream>>>(
            pooled, src5, pseudo5, mu2, sg2, g2, rt2, Ahi, Alo, Bthi, Btlo, n, cout, nbA);
        dim3 grid((n + 63) / 64, cout / 64, 2);
        gemm_mfma<<<grid, 256, 0, stream>>>(Ahi, Alo, Bthi, Btlo, CG, n, KK, cout);
        int L = 2562, tot = L * cout / 4;
        hexpool_reduce_kern<<<(tot + 255) / 256, 256, 0, stream>>>(CG, hex5, b2, pooled, L, cout, n, 2);
    }
    // ---- level 4: n=2562, cin=128, cout=256 — MFMA, z=2 ----
    {
        const int n = 2562, cout = 256, KK = 512;
        int nbA = (n + 1) / 2, nbW = KK * cout / 256;
        prep_kern<128><<<nbA + nbW, 256, 0, stream>>>(
            pooled, src4, pseudo4, mu3, sg3, g3, rt3, Ahi, Alo, Bthi, Btlo, n, cout, nbA);
        dim3 grid((n + 63) / 64, cout / 64, 2);
        gemm_mfma<<<grid, 256, 0, stream>>>(Ahi, Alo, Bthi, Btlo, CG, n, KK, cout);
        int L = 642, tot = L * cout / 4;
        hexpool_reduce_kern<<<(tot + 255) / 256, 256, 0, stream>>>(CG, hex4, b3, pooled, L, cout, n, 2);
    }
    // ---- level 3: n=642, cin=256, cout=512 — MFMA, z=4 ----
    {
        const int n = 642, cout = 512, KK = 1024;
        int nbA = n, nbW = KK * cout / 256;
        prep_kern<256><<<nbA + nbW, 256, 0, stream>>>(
            pooled, src3, pseudo3, mu4, sg4, g4, rt4, Ahi, Alo, Bthi, Btlo, n, cout, nbA);
        dim3 grid((n + 63) / 64, cout / 64, 4);
        gemm_mfma<<<grid, 256, 0, stream>>>(Ahi, Alo, Bthi, Btlo, CG, n, KK, cout);
        int L = 162, tot = L * cout / 4;
        hexpool_reduce_kern<<<(tot + 255) / 256, 256, 0, stream>>>(CG, hex3, b4, pooled, L, cout, n, 4);
    }
    // ---- head ----
    head1_kern<<<8, 256, 0, stream>>>(pooled, xc);
    {
        dim3 grid(8, 8);
        fc1_part_kern<<<grid, 256, 0, stream>>>(xc, fcW, fcpart);
    }
    head2_kern<<<1, 512, 0, stream>>>(fcpart, fcb, fc2W, fc2b, out);
}